// Round 6
// baseline (721.310 us; speedup 1.0000x reference)
//
#include <hip/hip_runtime.h>
#include <cstddef>

// ---------- constants ----------
#define BATCH 128
#define NV 128          // real visits per person
#define CPV 16
#define MAXV 510
#define SC 256          // compact sequence: [0..127]=real, [128]=pad-row, [129..255]=zero (masked)
#define NPAD 382        // number of identical pad rows the single pad row represents
#define DIM 256
#define NH 2
#define DH 128
#define NLAYERS 2
#define DFF 1024
#define MROWS (BATCH * SC)     // 32768 compact rows

typedef __attribute__((ext_vector_type(8))) short short8;
typedef __attribute__((ext_vector_type(4))) short short4v;
typedef __attribute__((ext_vector_type(4))) float floatx4;

__device__ __forceinline__ short f2bf(float f) {
    union { float f; unsigned u; } v; v.f = f;
    unsigned r = v.u + 0x7fffu + ((v.u >> 16) & 1u);
    return (short)(r >> 16);
}
__device__ __forceinline__ float bf2f(short s) {
    union { unsigned u; float f; } v; v.u = ((unsigned)(unsigned short)s) << 16;
    return v.f;
}

// ---------- all weight transposes in ONE launch ----------
// blockIdx.y = l*6 + w;  w: 0=Wq 1=Wk 2=Wv 3=Wo 4=W1 5=W2.  src f32 [K,N] -> dst bf16 [N,K]
__global__ __launch_bounds__(256) void wtrans_all(const float* __restrict__ Wq,
                                                  const float* __restrict__ Wk,
                                                  const float* __restrict__ Wv,
                                                  const float* __restrict__ Wo,
                                                  const float* __restrict__ W1,
                                                  const float* __restrict__ W2,
                                                  short* __restrict__ wqkvT,
                                                  short* __restrict__ woT,
                                                  short* __restrict__ w1T,
                                                  short* __restrict__ w2T) {
    int y = blockIdx.y;
    int l = y / 6, w = y - l * 6;
    const float* src; short* dst; int K, nsh;
    switch (w) {
        case 0:  src = Wq + (size_t)l * 65536;  dst = wqkvT + (size_t)l * 196608;           K = 256;  nsh = 8;  break;
        case 1:  src = Wk + (size_t)l * 65536;  dst = wqkvT + (size_t)l * 196608 + 65536;   K = 256;  nsh = 8;  break;
        case 2:  src = Wv + (size_t)l * 65536;  dst = wqkvT + (size_t)l * 196608 + 131072;  K = 256;  nsh = 8;  break;
        case 3:  src = Wo + (size_t)l * 65536;  dst = woT   + (size_t)l * 65536;            K = 256;  nsh = 8;  break;
        case 4:  src = W1 + (size_t)l * 262144; dst = w1T   + (size_t)l * 262144;           K = 256;  nsh = 10; break;
        default: src = W2 + (size_t)l * 262144; dst = w2T   + (size_t)l * 262144;           K = 1024; nsh = 8;  break;
    }
    int N = 1 << nsh;
    int idx = blockIdx.x * 256 + threadIdx.x;
    if (idx >= K * N) return;
    int k = idx >> nsh, n = idx & (N - 1);
    dst[(size_t)n * K + k] = f2bf(src[idx]);
}

// ---------- build compact x ----------
__global__ __launch_bounds__(256) void build_x(const int* __restrict__ codes,
                                               const float* __restrict__ times,
                                               const float* __restrict__ cemb,
                                               const float* __restrict__ pemb,
                                               short* __restrict__ x) {
    int row = blockIdx.x;          // b*SC + r
    int d = threadIdx.x;
    int b = row >> 8;
    int r = row & (SC - 1);
    float val;
    if (r > 128) {
        val = 0.f;
    } else if (r == 128) {
        val = pemb[d];
    } else {
        int visit = b * NV + r;
        const int* cb = codes + visit * CPV;
        float s = 0.f;
#pragma unroll
        for (int c = 0; c < CPV; ++c)
            s += cemb[(size_t)cb[c] * DIM + d];
        float t = times[visit];
        t = fminf(fmaxf(t, 0.f), 364.f);
        int i = d & 127;
        float ang = t * expf(-0.03597789207803197f * (float)i);
        float te = (d < 128) ? sinf(ang) : cosf(ang);
        val = s + te;
    }
    x[(size_t)row * DIM + d] = f2bf(val);
}

// ---------- merged QKV GEMM, direct-from-global fragments (zero LDS, zero barriers) ----------
__global__ __launch_bounds__(256) void gemm_qkv(const short* __restrict__ A,
                                                const short* __restrict__ BT,
                                                const float* __restrict__ bq,
                                                const float* __restrict__ bk,
                                                const float* __restrict__ bv,
                                                short* __restrict__ qo,
                                                short* __restrict__ ko,
                                                short* __restrict__ vo) {
    int tid = threadIdx.x;
    int wave = tid >> 6, lane = tid & 63;
    int l15 = lane & 15, quad = lane >> 4;
    int q8 = quad * 8;
    int m0 = blockIdx.y * 128;
    int n0 = blockIdx.x * 128;            // 0..640
    int sel = blockIdx.x >> 1;            // 0=q 1=k 2=v
    int nloc = n0 & 255;
    int wm = (wave & 1) * 64;
    int wn = (wave >> 1) * 64;

    const short* a0 = A  + (size_t)(m0 + wm + l15) * DIM + q8;
    const short* b0 = BT + (size_t)(n0 + wn + l15) * DIM + q8;

    floatx4 acc[4][4];
#pragma unroll
    for (int i = 0; i < 4; ++i)
#pragma unroll
        for (int j = 0; j < 4; ++j) acc[i][j] = (floatx4){0.f, 0.f, 0.f, 0.f};

#pragma unroll
    for (int k0 = 0; k0 < DIM; k0 += 32) {
        short8 aF[4], bF[4];
#pragma unroll
        for (int t = 0; t < 4; ++t) {
            aF[t] = *(const short8*)(a0 + (size_t)t * 16 * DIM + k0);
            bF[t] = *(const short8*)(b0 + (size_t)t * 16 * DIM + k0);
        }
#pragma unroll
        for (int i = 0; i < 4; ++i)
#pragma unroll
            for (int j = 0; j < 4; ++j)
                acc[i][j] = __builtin_amdgcn_mfma_f32_16x16x32_bf16(aF[i], bF[j], acc[i][j], 0, 0, 0);
    }

    const float* bias = (sel == 0) ? bq : (sel == 1) ? bk : bv;
    short* out = (sel == 0) ? qo : (sel == 1) ? ko : vo;
#pragma unroll
    for (int j = 0; j < 4; ++j) {
        int col = nloc + wn + j * 16 + l15;
        float bval = bias[col];
#pragma unroll
        for (int i = 0; i < 4; ++i) {
#pragma unroll
            for (int r = 0; r < 4; ++r) {
                int row = m0 + wm + i * 16 + quad * 4 + r;
                out[(size_t)row * DIM + col] = f2bf(acc[i][j][r] + bval);
            }
        }
    }
}

// ---------- Wo projection + residual + LN1; direct fragments, BM=64 ----------
__global__ __launch_bounds__(256) void gemm_wo_ln(const short* __restrict__ CTX,
                                                  const short* __restrict__ WoT,
                                                  const float* __restrict__ bo,
                                                  const short* __restrict__ X,
                                                  const float* __restrict__ g,
                                                  const float* __restrict__ bta,
                                                  short* __restrict__ xout) {
    int tid = threadIdx.x;
    int wave = tid >> 6, lane = tid & 63;
    int l15 = lane & 15, quad = lane >> 4;
    int q8 = quad * 8;
    int m0 = blockIdx.x * 64;
    int wr = wave * 16;

    const short* a0 = CTX + (size_t)(m0 + wr + l15) * DIM + q8;
    const short* b0 = WoT + (size_t)l15 * DIM + q8;

    floatx4 acc[16];
#pragma unroll
    for (int j = 0; j < 16; ++j) acc[j] = (floatx4){0.f, 0.f, 0.f, 0.f};

#pragma unroll
    for (int k0 = 0; k0 < DIM; k0 += 32) {
        short8 aF = *(const short8*)(a0 + k0);
#pragma unroll
        for (int j = 0; j < 16; ++j) {
            short8 bF = *(const short8*)(b0 + (size_t)j * 16 * DIM + k0);
            acc[j] = __builtin_amdgcn_mfma_f32_16x16x32_bf16(aF, bF, acc[j], 0, 0, 0);
        }
    }

    float bias[16], gam[16], bet[16];
#pragma unroll
    for (int j = 0; j < 16; ++j) {
        int col = j * 16 + l15;
        bias[j] = bo[col]; gam[j] = g[col]; bet[j] = bta[col];
    }
#pragma unroll
    for (int r = 0; r < 4; ++r) {
        int row = m0 + wr + quad * 4 + r;
        float v[16], s = 0.f, sq = 0.f;
#pragma unroll
        for (int j = 0; j < 16; ++j) {
            v[j] = acc[j][r] + bias[j] + bf2f(X[(size_t)row * DIM + j * 16 + l15]);
            s += v[j]; sq += v[j] * v[j];
        }
        s += __shfl_xor(s, 1); sq += __shfl_xor(sq, 1);
        s += __shfl_xor(s, 2); sq += __shfl_xor(sq, 2);
        s += __shfl_xor(s, 4); sq += __shfl_xor(sq, 4);
        s += __shfl_xor(s, 8); sq += __shfl_xor(sq, 8);
        float mean = s * (1.f / 256.f);
        float var = fmaxf(sq * (1.f / 256.f) - mean * mean, 0.f);
        float rstd = rsqrtf(var + 1e-5f);
#pragma unroll
        for (int j = 0; j < 16; ++j) {
            float y = gam[j] * (v[j] - mean) * rstd + bet[j];
            xout[(size_t)row * DIM + j * 16 + l15] = f2bf(y);
        }
    }
}

// ---------- fused FFN + LN2; direct weight fragments, only lP in LDS.  BM=64. ----------
#define PST 136
__global__ __launch_bounds__(256) void ff_fused(const short* __restrict__ X,
                                                const short* __restrict__ W1T,
                                                const float* __restrict__ b1,
                                                const short* __restrict__ W2T,
                                                const float* __restrict__ b2,
                                                const float* __restrict__ g2,
                                                const float* __restrict__ bt2,
                                                short* __restrict__ xout,
                                                float* __restrict__ fout,
                                                float* __restrict__ padrow) {
    __shared__ __align__(16) short lP[64 * PST];        // relu(ff1)  17 KiB
    __shared__ float redS[4][32], redQ[4][32];          //             1 KiB
    int tid = threadIdx.x;
    int wave = tid >> 6, lane = tid & 63;
    int l15 = lane & 15, quad = lane >> 4;
    int q8 = quad * 8;
    int m0 = blockIdx.x * 64;
    int wm = (wave & 1) * 32;        // row half (both GEMMs)
    int wf = (wave >> 1) * 64;       // dff cols (GEMM1)
    int wn2 = (wave >> 1) * 128;     // out cols (GEMM2)

    const short* x0 = X + (size_t)(m0 + wm + l15) * DIM + q8;      // t (<2) adds 16*DIM
    const short* w2 = W2T + (size_t)(wn2 + l15) * DFF + q8;        // j adds 16*DFF  (q8 FIX)

    floatx4 acc2[2][8];
#pragma unroll
    for (int i = 0; i < 2; ++i)
#pragma unroll
        for (int j = 0; j < 8; ++j) acc2[i][j] = (floatx4){0.f, 0.f, 0.f, 0.f};

    for (int f0 = 0; f0 < DFF; f0 += 128) {
        const short* w1 = W1T + (size_t)(f0 + wf + l15) * DIM + q8;
        floatx4 acc1[2][4];
#pragma unroll
        for (int i = 0; i < 2; ++i)
#pragma unroll
            for (int j = 0; j < 4; ++j) acc1[i][j] = (floatx4){0.f, 0.f, 0.f, 0.f};

#pragma unroll
        for (int k0 = 0; k0 < DIM; k0 += 32) {
            short8 aF[2], bF[4];
#pragma unroll
            for (int t = 0; t < 2; ++t)
                aF[t] = *(const short8*)(x0 + (size_t)t * 16 * DIM + k0);
#pragma unroll
            for (int t = 0; t < 4; ++t)
                bF[t] = *(const short8*)(w1 + (size_t)t * 16 * DIM + k0);
#pragma unroll
            for (int i = 0; i < 2; ++i)
#pragma unroll
                for (int j = 0; j < 4; ++j)
                    acc1[i][j] = __builtin_amdgcn_mfma_f32_16x16x32_bf16(aF[i], bF[j], acc1[i][j], 0, 0, 0);
        }

        // barrier: previous f0's GEMM2 finished reading lP before we overwrite it
        __syncthreads();
#pragma unroll
        for (int j = 0; j < 4; ++j) {
            int fc = wf + j * 16 + l15;
            float bval = b1[f0 + fc];
#pragma unroll
            for (int i = 0; i < 2; ++i) {
#pragma unroll
                for (int r = 0; r < 4; ++r) {
                    float v = acc1[i][j][r] + bval;
                    lP[(wm + i * 16 + quad * 4 + r) * PST + fc] = f2bf(fmaxf(v, 0.f));
                }
            }
        }
        __syncthreads();

        // GEMM2: aP from lP (LDS), bW direct from W2T (L2-hot)
#pragma unroll
        for (int ks = 0; ks < 4; ++ks) {
            short8 aP[2], bW[8];
#pragma unroll
            for (int t = 0; t < 2; ++t)
                aP[t] = *(const short8*)(lP + (wm + t * 16 + l15) * PST + ks * 32 + q8);
#pragma unroll
            for (int j = 0; j < 8; ++j)
                bW[j] = *(const short8*)(w2 + (size_t)j * 16 * DFF + f0 + ks * 32);
#pragma unroll
            for (int i = 0; i < 2; ++i)
#pragma unroll
                for (int j = 0; j < 8; ++j)
                    acc2[i][j] = __builtin_amdgcn_mfma_f32_16x16x32_bf16(aP[i], bW[j], acc2[i][j], 0, 0, 0);
        }
    }

    // ---- epilogue: residual + bias, then LN2 across the full 256-wide row ----
    __syncthreads();
    float b2v[8];
#pragma unroll
    for (int j = 0; j < 8; ++j) b2v[j] = b2[wn2 + j * 16 + l15];
#pragma unroll
    for (int i = 0; i < 2; ++i) {
#pragma unroll
        for (int r = 0; r < 4; ++r) {
            int row = m0 + wm + i * 16 + quad * 4 + r;
            float s = 0.f, sq = 0.f;
#pragma unroll
            for (int j = 0; j < 8; ++j) {
                float v = acc2[i][j][r] + b2v[j] + bf2f(X[(size_t)row * DIM + wn2 + j * 16 + l15]);
                acc2[i][j][r] = v;
                s += v; sq += v * v;
            }
            s += __shfl_xor(s, 1); sq += __shfl_xor(sq, 1);
            s += __shfl_xor(s, 2); sq += __shfl_xor(sq, 2);
            s += __shfl_xor(s, 4); sq += __shfl_xor(sq, 4);
            s += __shfl_xor(s, 8); sq += __shfl_xor(sq, 8);
            if (l15 == 0) {
                int idx = i * 16 + quad * 4 + r;
                redS[wave][idx] = s;
                redQ[wave][idx] = sq;
            }
        }
    }
    __syncthreads();
    float gam[8], bet[8];
#pragma unroll
    for (int j = 0; j < 8; ++j) {
        int col = wn2 + j * 16 + l15;
        gam[j] = g2[col]; bet[j] = bt2[col];
    }
#pragma unroll
    for (int i = 0; i < 2; ++i) {
#pragma unroll
        for (int r = 0; r < 4; ++r) {
            int idx = i * 16 + quad * 4 + r;
            float ts = redS[wave][idx] + redS[wave ^ 2][idx];
            float tq = redQ[wave][idx] + redQ[wave ^ 2][idx];
            float mean = ts * (1.f / 256.f);
            float var = fmaxf(tq * (1.f / 256.f) - mean * mean, 0.f);
            float rstd = rsqrtf(var + 1e-5f);
            int grow = m0 + wm + i * 16 + quad * 4 + r;
            if (!fout) {
#pragma unroll
                for (int j = 0; j < 8; ++j) {
                    float y = gam[j] * (acc2[i][j][r] - mean) * rstd + bet[j];
                    xout[(size_t)grow * DIM + wn2 + j * 16 + l15] = f2bf(y);
                }
            } else {
                int b = grow >> 8, rr = grow & 255;
                if (rr < 128) {
                    float* dst = fout + ((size_t)b * MAXV + NPAD + rr) * DIM;
#pragma unroll
                    for (int j = 0; j < 8; ++j) {
                        float y = gam[j] * (acc2[i][j][r] - mean) * rstd + bet[j];
                        dst[wn2 + j * 16 + l15] = y;
                    }
                } else if (rr == 128) {
#pragma unroll
                    for (int j = 0; j < 8; ++j) {
                        float y = gam[j] * (acc2[i][j][r] - mean) * rstd + bet[j];
                        padrow[(size_t)b * DIM + wn2 + j * 16 + l15] = y;
                    }
                }
            }
        }
    }
}

// ---------- pad-row broadcast: padrow[B][256] -> fout positions 0..NPAD-1 ----------
__global__ __launch_bounds__(256) void pad_bcast(const float* __restrict__ padrow,
                                                 float* __restrict__ fout) {
    int b = blockIdx.y;
    int p = blockIdx.x * 4 + (threadIdx.x >> 6);
    if (p >= NPAD) return;
    int d4 = (threadIdx.x & 63) * 4;
    floatx4 v = *(const floatx4*)(padrow + (size_t)b * DIM + d4);
    *(floatx4*)(fout + ((size_t)b * MAXV + p) * DIM + d4) = v;
}

// ---------- V transpose: v [M,256] -> vT [B*H][DH][SC] ----------
__global__ __launch_bounds__(256) void transpose_v(const short* __restrict__ v,
                                                   short* __restrict__ vT) {
    __shared__ short lds[32][33];
    int pair = blockIdx.y;
    int b = pair >> 1, h = pair & 1;
    int st = (blockIdx.x & 7) * 32;       // seq tile (SC/32 = 8)
    int dt = (blockIdx.x >> 3) * 32;      // dh tile  (DH/32 = 4)
    int tid = threadIdx.x;
    int sl = tid >> 3, dl = (tid & 7) * 4;
    const short* src = v + ((size_t)(b * SC + st + sl)) * DIM + h * DH + dt + dl;
    short4v val = *(const short4v*)src;
#pragma unroll
    for (int j = 0; j < 4; ++j) lds[sl][dl + j] = val[j];
    __syncthreads();
    int drow = tid >> 3, scol = (tid & 7) * 4;
    short* dst = vT + (size_t)pair * DH * SC + (size_t)(dt + drow) * SC + st + scol;
#pragma unroll
    for (int j = 0; j < 4; ++j) dst[j] = lds[scol + j][drow];
}

// ---------- fused attention; direct Q/K/V fragments, only lS in LDS ----------
#define AST 136
__global__ __launch_bounds__(256) void attn_fused(const short* __restrict__ q,
                                                  const short* __restrict__ k,
                                                  const short* __restrict__ vT,
                                                  short* __restrict__ ctx) {
    __shared__ __align__(16) short lS[128 * AST];  // 34 KiB weighted exp(S) chunk
    int tid = threadIdx.x;
    int wave = tid >> 6, lane = tid & 63;
    int l15 = lane & 15, quad = lane >> 4;
    int q8 = quad * 8;
    int pair = blockIdx.y;
    int b = pair >> 1, h = pair & 1;
    int m0 = blockIdx.x * 128;            // 0 or 128
    int wm = (wave & 1) * 64;
    int wn = (wave >> 1) * 64;

    const short* q0 = q  + ((size_t)(b * SC + m0 + wm + l15)) * DIM + h * DH + q8;  // t adds 16*DIM
    const short* k0p = k + ((size_t)(b * SC + wn + l15)) * DIM + h * DH + q8;       // kt adds 128*DIM
    const short* v0 = vT + (size_t)pair * DH * SC + (size_t)(wn + l15) * SC + q8;   // t adds 16*SC
    const float scale = 0.08838834764831845f;  // 1/sqrt(128)

    floatx4 oacc[4][4];
#pragma unroll
    for (int i = 0; i < 4; ++i)
#pragma unroll
        for (int j = 0; j < 4; ++j) oacc[i][j] = (floatx4){0.f, 0.f, 0.f, 0.f};
    float rsum[4] = {0.f, 0.f, 0.f, 0.f};

    for (int kt = 0; kt < 2; ++kt) {
        // ---- QK: sacc = Q[m-tile] . K[kt-chunk]^T  (no LDS, no barriers) ----
        floatx4 sacc[4][4];
#pragma unroll
        for (int i = 0; i < 4; ++i)
#pragma unroll
            for (int j = 0; j < 4; ++j) sacc[i][j] = (floatx4){0.f, 0.f, 0.f, 0.f};
#pragma unroll
        for (int c0 = 0; c0 < DH; c0 += 32) {
            short8 aF[4], bF[4];
#pragma unroll
            for (int t = 0; t < 4; ++t) {
                aF[t] = *(const short8*)(q0 + (size_t)t * 16 * DIM + c0);
                bF[t] = *(const short8*)(k0p + (size_t)(kt * 128 + t * 16) * DIM + c0);
            }
#pragma unroll
            for (int i = 0; i < 4; ++i)
#pragma unroll
                for (int j = 0; j < 4; ++j)
                    sacc[i][j] = __builtin_amdgcn_mfma_f32_16x16x32_bf16(aF[i], bF[j], sacc[i][j], 0, 0, 0);
        }
        // ---- weighted exp + mask -> lS ----
        __syncthreads();   // previous kt's PV readers of lS are done
#pragma unroll
        for (int j = 0; j < 4; ++j) {
            int col = wn + j * 16 + l15;
            int cg = kt * 128 + col;
            float w = (cg < 128) ? 1.f : ((cg == 128) ? (float)NPAD : 0.f);
#pragma unroll
            for (int i = 0; i < 4; ++i) {
#pragma unroll
                for (int r = 0; r < 4; ++r) {
                    float e = __expf(fminf(sacc[i][j][r] * scale, 30.f));
                    lS[(wm + i * 16 + quad * 4 + r) * AST + col] = f2bf(w * e);
                }
            }
        }
        __syncthreads();
        // ---- PV: oacc += lS . V[kt-chunk]  (bV direct from vT) ----
#pragma unroll
        for (int ks = 0; ks < 4; ++ks) {
            short8 aP[4], bV[4];
#pragma unroll
            for (int t = 0; t < 4; ++t) {
                aP[t] = *(const short8*)(lS + (wm + t * 16 + l15) * AST + ks * 32 + q8);
                bV[t] = *(const short8*)(v0 + (size_t)t * 16 * SC + kt * 128 + ks * 32);
            }
#pragma unroll
            for (int i = 0; i < 4; ++i) {
                float s = 0.f;
#pragma unroll
                for (int e = 0; e < 8; ++e) s += bf2f(aP[i][e]);
                rsum[i] += s;
            }
#pragma unroll
            for (int i = 0; i < 4; ++i)
#pragma unroll
                for (int j = 0; j < 4; ++j)
                    oacc[i][j] = __builtin_amdgcn_mfma_f32_16x16x32_bf16(aP[i], bV[j], oacc[i][j], 0, 0, 0);
        }
    }

    // ---- epilogue: /rowsum, write ctx ----
#pragma unroll
    for (int i = 0; i < 4; ++i) {
        rsum[i] += __shfl_xor(rsum[i], 16);
        rsum[i] += __shfl_xor(rsum[i], 32);
    }
    short* outb = ctx + ((size_t)(b * SC + m0)) * DIM + h * DH;
#pragma unroll
    for (int i = 0; i < 4; ++i) {
#pragma unroll
        for (int r = 0; r < 4; ++r) {
            float inv = 1.f / __shfl(rsum[i], quad * 4 + r);
#pragma unroll
            for (int j = 0; j < 4; ++j) {
                int col = wn + j * 16 + l15;
                int row = wm + i * 16 + quad * 4 + r;
                outb[(size_t)row * DIM + col] = f2bf(oacc[i][j][r] * inv);
            }
        }
    }
}

extern "C" void kernel_launch(void* const* d_in, const int* in_sizes, int n_in,
                              void* d_out, int out_size, void* d_ws, size_t ws_size,
                              hipStream_t stream) {
    const int*   all_codes = (const int*)d_in[0];
    const float* times = (const float*)d_in[3];
    const float* cemb  = (const float*)d_in[4];
    const float* pemb  = (const float*)d_in[5];
    const float* Wq = (const float*)d_in[6];
    const float* Wk = (const float*)d_in[7];
    const float* Wv = (const float*)d_in[8];
    const float* Wo = (const float*)d_in[9];
    const float* bq = (const float*)d_in[10];
    const float* bk = (const float*)d_in[11];
    const float* bv = (const float*)d_in[12];
    const float* bo = (const float*)d_in[13];
    const float* ln1g = (const float*)d_in[14];
    const float* ln1b = (const float*)d_in[15];
    const float* W1 = (const float*)d_in[16];
    const float* b1 = (const float*)d_in[17];
    const float* W2 = (const float*)d_in[18];
    const float* b2 = (const float*)d_in[19];
    const float* ln2g = (const float*)d_in[20];
    const float* ln2b = (const float*)d_in[21];

    char* ws = (char*)d_ws;
    short* wqkvT = (short*)ws;                    // [2][768*256]
    short* woT   = wqkvT + 2 * 196608;            // [2][256*256]
    short* w1T   = woT + 2 * 65536;               // [2][1024*256]
    short* w2T   = w1T + 2 * 262144;              // [2][256*1024]
    float* padrow = (float*)(ws + (3500u << 10)); // [128][256] f32, 128 KiB

    const size_t SLOT = (size_t)MROWS * DIM;      // 32768*256 shorts = 16 MiB
    short* xb = (short*)(ws + (4u << 20));
    short* C0 = xb + SLOT;     // q -> h1 (LN1 out)
    short* C1 = C0 + SLOT;     // k
    short* C2 = C1 + SLOT;     // v
    short* C3 = C2 + SLOT;     // ctx
    short* C4 = C3 + SLOT;     // vT

    wtrans_all<<<dim3(1024, 12), 256, 0, stream>>>(Wq, Wk, Wv, Wo, W1, W2,
                                                   wqkvT, woT, w1T, w2T);
    build_x<<<MROWS, 256, 0, stream>>>(all_codes, times, cemb, pemb, xb);

    for (int l = 0; l < NLAYERS; ++l) {
        const short* qkv_l = wqkvT + (size_t)l * 196608;
        const short* wo_l = woT + (size_t)l * 65536;
        const short* w1_l = w1T + (size_t)l * 262144;
        const short* w2_l = w2T + (size_t)l * 262144;
        int last = (l == NLAYERS - 1);

        gemm_qkv<<<dim3(6, MROWS / 128), 256, 0, stream>>>(xb, qkv_l, bq + l * 256, bk + l * 256,
                                                           bv + l * 256, C0, C1, C2);
        transpose_v<<<dim3(32, BATCH * NH), 256, 0, stream>>>(C2, C4);
        attn_fused<<<dim3(2, BATCH * NH), 256, 0, stream>>>(C0, C1, C4, C3);
        // h1 = LN1(x + ctx@Wo + bo): reads C3 + xb, writes C0. No aliasing.
        gemm_wo_ln<<<MROWS / 64, 256, 0, stream>>>(C3, wo_l, bo + l * 256, xb,
                                                   ln1g + l * 256, ln1b + l * 256, C0);
        // x = LN2(h1 + ffn(h1)): reads C0, writes xb (or f32 fout + padrow on last layer).
        ff_fused<<<MROWS / 64, 256, 0, stream>>>(C0, w1_l, b1 + l * 1024, w2_l, b2 + l * 256,
                                                 ln2g + l * 256, ln2b + l * 256, xb,
                                                 last ? (float*)d_out : nullptr,
                                                 last ? padrow : nullptr);
        if (last)
            pad_bcast<<<dim3(96, BATCH), 256, 0, stream>>>(padrow, (float*)d_out);
    }
}

// Round 8
// 539.695 us; speedup vs baseline: 1.3365x; 1.3365x over previous
//
#include <hip/hip_runtime.h>
#include <cstddef>

// ---------- constants ----------
#define BATCH 128
#define NV 128          // real visits per person
#define CPV 16
#define MAXV 510
#define NPAD 382        // identical pad rows represented by one side-path row per batch
#define DIM 256
#define NH 2
#define DH 128
#define NLAYERS 2
#define DFF 1024
#define MROWS (BATCH * NV)     // 16384 packed REAL rows (row = b*128 + r)
#define AST 168                // lS row stride (bank-friendly: 84 dwords, 2-way max)
#define VST 160                // vT seq stride (128 keys + 32-tail)

typedef __attribute__((ext_vector_type(8))) short short8;
typedef __attribute__((ext_vector_type(4))) short short4v;
typedef __attribute__((ext_vector_type(4))) float floatx4;

__device__ __forceinline__ short f2bf(float f) {
    union { float f; unsigned u; } v; v.f = f;
    unsigned r = v.u + 0x7fffu + ((v.u >> 16) & 1u);
    return (short)(r >> 16);
}
__device__ __forceinline__ float bf2f(short s) {
    union { unsigned u; float f; } v; v.u = ((unsigned)(unsigned short)s) << 16;
    return v.f;
}

__device__ __forceinline__ void gload_lds16(const short* g, short* l) {
    __builtin_amdgcn_global_load_lds(
        (const __attribute__((address_space(1))) unsigned int*)g,
        (__attribute__((address_space(3))) unsigned int*)l,
        16, 0, 0);
}

// ---------- all weight transposes in ONE launch ----------
__global__ __launch_bounds__(256) void wtrans_all(const float* __restrict__ Wq,
                                                  const float* __restrict__ Wk,
                                                  const float* __restrict__ Wv,
                                                  const float* __restrict__ Wo,
                                                  const float* __restrict__ W1,
                                                  const float* __restrict__ W2,
                                                  short* __restrict__ wqkvT,
                                                  short* __restrict__ woT,
                                                  short* __restrict__ w1T,
                                                  short* __restrict__ w2T) {
    int y = blockIdx.y;
    int l = y / 6, w = y - l * 6;
    const float* src; short* dst; int K, nsh;
    switch (w) {
        case 0:  src = Wq + (size_t)l * 65536;  dst = wqkvT + (size_t)l * 196608;           K = 256;  nsh = 8;  break;
        case 1:  src = Wk + (size_t)l * 65536;  dst = wqkvT + (size_t)l * 196608 + 65536;   K = 256;  nsh = 8;  break;
        case 2:  src = Wv + (size_t)l * 65536;  dst = wqkvT + (size_t)l * 196608 + 131072;  K = 256;  nsh = 8;  break;
        case 3:  src = Wo + (size_t)l * 65536;  dst = woT   + (size_t)l * 65536;            K = 256;  nsh = 8;  break;
        case 4:  src = W1 + (size_t)l * 262144; dst = w1T   + (size_t)l * 262144;           K = 256;  nsh = 10; break;
        default: src = W2 + (size_t)l * 262144; dst = w2T   + (size_t)l * 262144;           K = 1024; nsh = 8;  break;
    }
    int N = 1 << nsh;
    int idx = blockIdx.x * 256 + threadIdx.x;
    if (idx >= K * N) return;
    int k = idx >> nsh, n = idx & (N - 1);
    dst[(size_t)n * K + k] = f2bf(src[idx]);
}

// ---------- build packed x (real rows only) ----------
__global__ __launch_bounds__(256) void build_x(const int* __restrict__ codes,
                                               const float* __restrict__ times,
                                               const float* __restrict__ cemb,
                                               short* __restrict__ x) {
    int row = blockIdx.x;          // b*128 + r
    int d = threadIdx.x;
    int b = row >> 7;
    int r = row & 127;
    int visit = b * NV + r;
    const int* cb = codes + visit * CPV;
    float s = 0.f;
#pragma unroll
    for (int c = 0; c < CPV; ++c)
        s += cemb[(size_t)cb[c] * DIM + d];
    float t = times[visit];
    t = fminf(fmaxf(t, 0.f), 364.f);
    int i = d & 127;
    float ang = t * expf(-0.03597789207803197f * (float)i);
    float te = (d < 128) ? sinf(ang) : cosf(ang);
    x[(size_t)row * DIM + d] = f2bf(s + te);
}

// ---------- build pad-row x (one row per batch, = pad_emb) ----------
__global__ __launch_bounds__(256) void build_xpad(const float* __restrict__ pemb,
                                                  short* __restrict__ xpad) {
    xpad[(size_t)blockIdx.x * DIM + threadIdx.x] = f2bf(pemb[threadIdx.x]);
}

// ---------- merged QKV GEMM (2-phase dbuf): BT = [WqT; WkT; WvT] ----------
__global__ __launch_bounds__(256) void gemm_qkv(const short* __restrict__ A,
                                                const short* __restrict__ BT,
                                                const float* __restrict__ bq,
                                                const float* __restrict__ bk,
                                                const float* __restrict__ bv,
                                                short* __restrict__ qo,
                                                short* __restrict__ ko,
                                                short* __restrict__ vo) {
    __shared__ __align__(16) short lA[2][128 * 32];
    __shared__ __align__(16) short lB[2][128 * 32];
    int tid = threadIdx.x;
    int wave = tid >> 6, lane = tid & 63;
    int l15 = lane & 15, quad = lane >> 4;
    int q8 = quad * 8;
    int m0 = blockIdx.y * 128;
    int n0 = blockIdx.x * 128;
    int sel = blockIdx.x >> 1;
    int nloc = n0 & 255;
    int wm = (wave & 1) * 64;
    int wn = (wave >> 1) * 64;

    int srow = tid >> 2;
    int skoff = (tid & 3) * 8;
    const short* ag = A + (size_t)(m0 + srow) * DIM + skoff;
    const short* bg = BT + (size_t)(n0 + srow) * DIM + skoff;
    const size_t rstep = (size_t)64 * DIM;
    int t8 = tid * 8;

    floatx4 acc[4][4];
#pragma unroll
    for (int i = 0; i < 4; ++i)
#pragma unroll
        for (int j = 0; j < 4; ++j) acc[i][j] = (floatx4){0.f, 0.f, 0.f, 0.f};

    gload_lds16(ag, lA[0] + t8);
    gload_lds16(ag + rstep, lA[0] + 2048 + t8);
    gload_lds16(bg, lB[0] + t8);
    gload_lds16(bg + rstep, lB[0] + 2048 + t8);
    __syncthreads();
    int cur = 0;
#pragma unroll
    for (int k0 = 0; k0 < 8; ++k0) {
        if (k0 < 7) {
            int kn = (k0 + 1) * 32;
            gload_lds16(ag + kn, lA[cur ^ 1] + t8);
            gload_lds16(ag + rstep + kn, lA[cur ^ 1] + 2048 + t8);
            gload_lds16(bg + kn, lB[cur ^ 1] + t8);
            gload_lds16(bg + rstep + kn, lB[cur ^ 1] + 2048 + t8);
        }
        short8 aF[4], bF[4];
#pragma unroll
        for (int t = 0; t < 4; ++t) {
            aF[t] = *(const short8*)(lA[cur] + (wm + t * 16 + l15) * 32 + q8);
            bF[t] = *(const short8*)(lB[cur] + (wn + t * 16 + l15) * 32 + q8);
        }
#pragma unroll
        for (int i = 0; i < 4; ++i)
#pragma unroll
            for (int j = 0; j < 4; ++j)
                acc[i][j] = __builtin_amdgcn_mfma_f32_16x16x32_bf16(aF[i], bF[j], acc[i][j], 0, 0, 0);
        __syncthreads();
        cur ^= 1;
    }

    const float* bias = (sel == 0) ? bq : (sel == 1) ? bk : bv;
    short* out = (sel == 0) ? qo : (sel == 1) ? ko : vo;
#pragma unroll
    for (int j = 0; j < 4; ++j) {
        int col = nloc + wn + j * 16 + l15;
        float bval = bias[col];
#pragma unroll
        for (int i = 0; i < 4; ++i) {
#pragma unroll
            for (int r = 0; r < 4; ++r) {
                int row = m0 + wm + i * 16 + quad * 4 + r;
                out[(size_t)row * DIM + col] = f2bf(acc[i][j][r] + bval);
            }
        }
    }
}

// ---------- pad-row QKV (GEMV per batch) ----------
__global__ __launch_bounds__(256) void pad_qkv(const short* __restrict__ xpad,
                                               const short* __restrict__ qkvT,
                                               const float* __restrict__ bq,
                                               const float* __restrict__ bk,
                                               const float* __restrict__ bv,
                                               float* __restrict__ padQ,
                                               short* __restrict__ padK,
                                               short* __restrict__ padV) {
    __shared__ float x[256];
    int b = blockIdx.x, tid = threadIdx.x;
    x[tid] = bf2f(xpad[(size_t)b * DIM + tid]);
    __syncthreads();
#pragma unroll
    for (int w = 0; w < 3; ++w) {
        const short* wr = qkvT + (size_t)w * 65536 + (size_t)tid * 256;
        float a = 0.f;
#pragma unroll 8
        for (int k = 0; k < 256; ++k) a += x[k] * bf2f(wr[k]);
        if (w == 0)      padQ[(size_t)b * DIM + tid] = a + bq[tid];
        else if (w == 1) padK[(size_t)b * DIM + tid] = f2bf(a + bk[tid]);
        else             padV[(size_t)b * DIM + tid] = f2bf(a + bv[tid]);
    }
}

// ---------- Wo projection + residual + LN1 (2-phase dbuf).  BM=64. ----------
__global__ __launch_bounds__(256) void gemm_wo_ln(const short* __restrict__ CTX,
                                                  const short* __restrict__ WoT,
                                                  const float* __restrict__ bo,
                                                  const short* __restrict__ X,
                                                  const float* __restrict__ g,
                                                  const float* __restrict__ bta,
                                                  short* __restrict__ xout) {
    __shared__ __align__(16) short lA[2][64 * 32];
    __shared__ __align__(16) short lB[2][256 * 32];
    int tid = threadIdx.x;
    int wave = tid >> 6, lane = tid & 63;
    int l15 = lane & 15, quad = lane >> 4;
    int q8 = quad * 8;
    int m0 = blockIdx.x * 64;
    int wr = wave * 16;
    int srow = tid >> 2;
    int skoff = (tid & 3) * 8;
    const short* ag = CTX + (size_t)(m0 + srow) * DIM + skoff;
    const short* bg = WoT + (size_t)srow * DIM + skoff;
    int t8 = tid * 8;

    floatx4 acc[16];
#pragma unroll
    for (int j = 0; j < 16; ++j) acc[j] = (floatx4){0.f, 0.f, 0.f, 0.f};

    gload_lds16(ag, lA[0] + t8);
    gload_lds16(bg, lB[0] + t8);
    gload_lds16(bg + (size_t)64 * DIM, lB[0] + 2048 + t8);
    gload_lds16(bg + (size_t)128 * DIM, lB[0] + 4096 + t8);
    gload_lds16(bg + (size_t)192 * DIM, lB[0] + 6144 + t8);
    __syncthreads();
    int cur = 0;
#pragma unroll
    for (int k0 = 0; k0 < 8; ++k0) {
        if (k0 < 7) {
            int kn = (k0 + 1) * 32;
            gload_lds16(ag + kn, lA[cur ^ 1] + t8);
            gload_lds16(bg + kn, lB[cur ^ 1] + t8);
            gload_lds16(bg + (size_t)64 * DIM + kn, lB[cur ^ 1] + 2048 + t8);
            gload_lds16(bg + (size_t)128 * DIM + kn, lB[cur ^ 1] + 4096 + t8);
            gload_lds16(bg + (size_t)192 * DIM + kn, lB[cur ^ 1] + 6144 + t8);
        }
        short8 aF = *(const short8*)(lA[cur] + (wr + l15) * 32 + q8);
#pragma unroll
        for (int j = 0; j < 16; ++j) {
            short8 bF = *(const short8*)(lB[cur] + (j * 16 + l15) * 32 + q8);
            acc[j] = __builtin_amdgcn_mfma_f32_16x16x32_bf16(aF, bF, acc[j], 0, 0, 0);
        }
        __syncthreads();
        cur ^= 1;
    }

    float bias[16], gam[16], bet[16];
#pragma unroll
    for (int j = 0; j < 16; ++j) {
        int col = j * 16 + l15;
        bias[j] = bo[col]; gam[j] = g[col]; bet[j] = bta[col];
    }
#pragma unroll
    for (int r = 0; r < 4; ++r) {
        int row = m0 + wr + quad * 4 + r;
        float v[16], s = 0.f, sq = 0.f;
#pragma unroll
        for (int j = 0; j < 16; ++j) {
            v[j] = acc[j][r] + bias[j] + bf2f(X[(size_t)row * DIM + j * 16 + l15]);
            s += v[j]; sq += v[j] * v[j];
        }
        s += __shfl_xor(s, 1); sq += __shfl_xor(sq, 1);
        s += __shfl_xor(s, 2); sq += __shfl_xor(sq, 2);
        s += __shfl_xor(s, 4); sq += __shfl_xor(sq, 4);
        s += __shfl_xor(s, 8); sq += __shfl_xor(sq, 8);
        float mean = s * (1.f / 256.f);
        float var = fmaxf(sq * (1.f / 256.f) - mean * mean, 0.f);
        float rstd = rsqrtf(var + 1e-5f);
#pragma unroll
        for (int j = 0; j < 16; ++j) {
            float y = gam[j] * (v[j] - mean) * rstd + bet[j];
            xout[(size_t)row * DIM + j * 16 + l15] = f2bf(y);
        }
    }
}

// ---------- fused FFN + LN2 (2-phase dbuf), BM=64 ----------
#define PST 136
__global__ __launch_bounds__(256, 2) void ff_fused(const short* __restrict__ X,
                                                   const short* __restrict__ W1T,
                                                   const float* __restrict__ b1,
                                                   const short* __restrict__ W2T,
                                                   const float* __restrict__ b2,
                                                   const float* __restrict__ g2,
                                                   const float* __restrict__ bt2,
                                                   short* __restrict__ xout,
                                                   float* __restrict__ fout) {
    __shared__ __align__(16) short lA[2][64 * 32];
    __shared__ __align__(16) short lB[2][128 * 32];
    __shared__ __align__(16) short lB2[2][256 * 32];
    __shared__ __align__(16) short lP[64 * PST];
    __shared__ float redS[4][32], redQ[4][32];
    int tid = threadIdx.x;
    int wave = tid >> 6, lane = tid & 63;
    int l15 = lane & 15, quad = lane >> 4;
    int q8 = quad * 8;
    int m0 = blockIdx.x * 64;
    int wm = (wave & 1) * 32;
    int wf = (wave >> 1) * 64;
    int wn2 = (wave >> 1) * 128;
    int srow = tid >> 2;
    int spart = (tid & 3) * 8;
    const short* xg = X + (size_t)(m0 + srow) * DIM + spart;
    int t8 = tid * 8;

    floatx4 acc2[2][8];
#pragma unroll
    for (int i = 0; i < 2; ++i)
#pragma unroll
        for (int j = 0; j < 8; ++j) acc2[i][j] = (floatx4){0.f, 0.f, 0.f, 0.f};

    for (int f0 = 0; f0 < DFF; f0 += 128) {
        const short* w1g = W1T + (size_t)(f0 + srow) * DIM + spart;
        floatx4 acc1[2][4];
#pragma unroll
        for (int i = 0; i < 2; ++i)
#pragma unroll
            for (int j = 0; j < 4; ++j) acc1[i][j] = (floatx4){0.f, 0.f, 0.f, 0.f};

        gload_lds16(xg, lA[0] + t8);
        gload_lds16(w1g, lB[0] + t8);
        gload_lds16(w1g + (size_t)64 * DIM, lB[0] + 2048 + t8);
        __syncthreads();
        int cur = 0;
#pragma unroll
        for (int k0 = 0; k0 < 8; ++k0) {
            if (k0 < 7) {
                int kn = (k0 + 1) * 32;
                gload_lds16(xg + kn, lA[cur ^ 1] + t8);
                gload_lds16(w1g + kn, lB[cur ^ 1] + t8);
                gload_lds16(w1g + (size_t)64 * DIM + kn, lB[cur ^ 1] + 2048 + t8);
            }
            short8 aF[2], bF[4];
#pragma unroll
            for (int t = 0; t < 2; ++t)
                aF[t] = *(const short8*)(lA[cur] + (wm + t * 16 + l15) * 32 + q8);
#pragma unroll
            for (int t = 0; t < 4; ++t)
                bF[t] = *(const short8*)(lB[cur] + (wf + t * 16 + l15) * 32 + q8);
#pragma unroll
            for (int i = 0; i < 2; ++i)
#pragma unroll
                for (int j = 0; j < 4; ++j)
                    acc1[i][j] = __builtin_amdgcn_mfma_f32_16x16x32_bf16(aF[i], bF[j], acc1[i][j], 0, 0, 0);
            __syncthreads();
            cur ^= 1;
        }

        {
            const short* w2g = W2T + (size_t)srow * DFF + f0 + spart;
            gload_lds16(w2g, lB2[0] + t8);
            gload_lds16(w2g + (size_t)64 * DFF, lB2[0] + 2048 + t8);
            gload_lds16(w2g + (size_t)128 * DFF, lB2[0] + 4096 + t8);
            gload_lds16(w2g + (size_t)192 * DFF, lB2[0] + 6144 + t8);
        }
#pragma unroll
        for (int j = 0; j < 4; ++j) {
            int fc = wf + j * 16 + l15;
            float bval = b1[f0 + fc];
#pragma unroll
            for (int i = 0; i < 2; ++i) {
#pragma unroll
                for (int r = 0; r < 4; ++r) {
                    float v = acc1[i][j][r] + bval;
                    lP[(wm + i * 16 + quad * 4 + r) * PST + fc] = f2bf(fmaxf(v, 0.f));
                }
            }
        }
        __syncthreads();
        cur = 0;
#pragma unroll
        for (int ks = 0; ks < 4; ++ks) {
            if (ks < 3) {
                const short* w2g = W2T + (size_t)srow * DFF + f0 + (ks + 1) * 32 + spart;
                gload_lds16(w2g, lB2[cur ^ 1] + t8);
                gload_lds16(w2g + (size_t)64 * DFF, lB2[cur ^ 1] + 2048 + t8);
                gload_lds16(w2g + (size_t)128 * DFF, lB2[cur ^ 1] + 4096 + t8);
                gload_lds16(w2g + (size_t)192 * DFF, lB2[cur ^ 1] + 6144 + t8);
            }
            short8 aP[2], bW[8];
#pragma unroll
            for (int t = 0; t < 2; ++t)
                aP[t] = *(const short8*)(lP + (wm + t * 16 + l15) * PST + ks * 32 + q8);
#pragma unroll
            for (int j = 0; j < 8; ++j)
                bW[j] = *(const short8*)(lB2[cur] + (wn2 + j * 16 + l15) * 32 + q8);
#pragma unroll
            for (int i = 0; i < 2; ++i)
#pragma unroll
                for (int j = 0; j < 8; ++j)
                    acc2[i][j] = __builtin_amdgcn_mfma_f32_16x16x32_bf16(aP[i], bW[j], acc2[i][j], 0, 0, 0);
            __syncthreads();
            cur ^= 1;
        }
    }

    // ---- epilogue: residual + bias, LN2 over full row ----
    float b2v[8];
#pragma unroll
    for (int j = 0; j < 8; ++j) b2v[j] = b2[wn2 + j * 16 + l15];
#pragma unroll
    for (int i = 0; i < 2; ++i) {
#pragma unroll
        for (int r = 0; r < 4; ++r) {
            int row = m0 + wm + i * 16 + quad * 4 + r;
            float s = 0.f, sq = 0.f;
#pragma unroll
            for (int j = 0; j < 8; ++j) {
                float v = acc2[i][j][r] + b2v[j] + bf2f(X[(size_t)row * DIM + wn2 + j * 16 + l15]);
                acc2[i][j][r] = v;
                s += v; sq += v * v;
            }
            s += __shfl_xor(s, 1); sq += __shfl_xor(sq, 1);
            s += __shfl_xor(s, 2); sq += __shfl_xor(sq, 2);
            s += __shfl_xor(s, 4); sq += __shfl_xor(sq, 4);
            s += __shfl_xor(s, 8); sq += __shfl_xor(sq, 8);
            if (l15 == 0) {
                int idx = i * 16 + quad * 4 + r;
                redS[wave][idx] = s;
                redQ[wave][idx] = sq;
            }
        }
    }
    __syncthreads();
    float gam[8], bet[8];
#pragma unroll
    for (int j = 0; j < 8; ++j) {
        int col = wn2 + j * 16 + l15;
        gam[j] = g2[col]; bet[j] = bt2[col];
    }
#pragma unroll
    for (int i = 0; i < 2; ++i) {
#pragma unroll
        for (int r = 0; r < 4; ++r) {
            int idx = i * 16 + quad * 4 + r;
            float ts = redS[wave][idx] + redS[wave ^ 2][idx];
            float tq = redQ[wave][idx] + redQ[wave ^ 2][idx];
            float mean = ts * (1.f / 256.f);
            float var = fmaxf(tq * (1.f / 256.f) - mean * mean, 0.f);
            float rstd = rsqrtf(var + 1e-5f);
            int grow = m0 + wm + i * 16 + quad * 4 + r;
            if (!fout) {
#pragma unroll
                for (int j = 0; j < 8; ++j) {
                    float y = gam[j] * (acc2[i][j][r] - mean) * rstd + bet[j];
                    xout[(size_t)grow * DIM + wn2 + j * 16 + l15] = f2bf(y);
                }
            } else {
                int bb = grow >> 7, rr = grow & 127;
                float* dst = fout + ((size_t)bb * MAXV + NPAD + rr) * DIM;
#pragma unroll
                for (int j = 0; j < 8; ++j) {
                    float y = gam[j] * (acc2[i][j][r] - mean) * rstd + bet[j];
                    dst[wn2 + j * 16 + l15] = y;
                }
            }
        }
    }
}

// ---------- pad-row full layer pipeline (attn + Wo/LN1 + FFN/LN2), one block per batch ----------
__global__ __launch_bounds__(256) void pad_tail(const float* __restrict__ padQ,
                                                const short* __restrict__ padK,
                                                const short* __restrict__ padV,
                                                const short* __restrict__ kmain,
                                                const short* __restrict__ vmain,
                                                const short* __restrict__ woT,
                                                const float* __restrict__ bo,
                                                const float* __restrict__ g1,
                                                const float* __restrict__ bt1,
                                                const short* __restrict__ w1T,
                                                const float* __restrict__ b1,
                                                const short* __restrict__ w2T,
                                                const float* __restrict__ b2,
                                                const float* __restrict__ g2,
                                                const float* __restrict__ bt2,
                                                short* __restrict__ xpad,
                                                float* __restrict__ padrowF) {
    __shared__ float qv[256], wgt[2][128], wp[2], den[2], ctx[256], h1[256], ff[1024];
    __shared__ float red[4][2];
    int b = blockIdx.x, tid = threadIdx.x;
    int wave = tid >> 6, lane = tid & 63;
    const float scale = 0.08838834764831845f;

    qv[tid] = padQ[(size_t)b * DIM + tid];
    __syncthreads();
    int h = tid >> 7, kk = tid & 127;
    // scores vs 128 real keys
    {
        const short* krow = kmain + (size_t)(b * NV + kk) * DIM + h * DH;
        float s = 0.f;
#pragma unroll 8
        for (int d = 0; d < DH; ++d) s += bf2f(krow[d]) * qv[h * DH + d];
        wgt[h][kk] = __expf(fminf(s * scale, 30.f));
    }
    // score vs pad key (weight 382)
    if (kk == 0) {
        const short* kp = padK + (size_t)b * DIM + h * DH;
        float sp = 0.f;
#pragma unroll 8
        for (int d = 0; d < DH; ++d) sp += bf2f(kp[d]) * qv[h * DH + d];
        wp[h] = 382.f * __expf(fminf(sp * scale, 30.f));
    }
    __syncthreads();
    if (kk == 0) {
        float dsum = wp[h];
        for (int i = 0; i < 128; ++i) dsum += wgt[h][i];
        den[h] = dsum;
    }
    __syncthreads();
    // ctx
    {
        const short* vcol = vmain + (size_t)(b * NV) * DIM + h * DH + kk;
        float c = 0.f;
#pragma unroll 8
        for (int key = 0; key < 128; ++key) c += wgt[h][key] * bf2f(vcol[(size_t)key * DIM]);
        c += wp[h] * bf2f(padV[(size_t)b * DIM + h * DH + kk]);
        ctx[h * DH + kk] = c / den[h];
    }
    __syncthreads();
    // h1 = LN1(xpad + ctx@Wo + bo)
    float t;
    {
        const short* wr = woT + (size_t)tid * 256;
        float a = 0.f;
#pragma unroll 8
        for (int k = 0; k < 256; ++k) a += ctx[k] * bf2f(wr[k]);
        t = a + bo[tid] + bf2f(xpad[(size_t)b * DIM + tid]);
    }
    {
        float s = t, sq = t * t;
#pragma unroll
        for (int off = 1; off < 64; off <<= 1) { s += __shfl_xor(s, off); sq += __shfl_xor(sq, off); }
        if (lane == 0) { red[wave][0] = s; red[wave][1] = sq; }
        __syncthreads();
        float ts = red[0][0] + red[1][0] + red[2][0] + red[3][0];
        float tq = red[0][1] + red[1][1] + red[2][1] + red[3][1];
        float mean = ts * (1.f / 256.f);
        float var = fmaxf(tq * (1.f / 256.f) - mean * mean, 0.f);
        float rstd = rsqrtf(var + 1e-5f);
        h1[tid] = g1[tid] * (t - mean) * rstd + bt1[tid];
    }
    __syncthreads();
    // ff1 (4 outputs per thread)
#pragma unroll
    for (int u = 0; u < 4; ++u) {
        int f = u * 256 + tid;
        const short* wr = w1T + (size_t)f * 256;
        float a = 0.f;
#pragma unroll 8
        for (int k = 0; k < 256; ++k) a += h1[k] * bf2f(wr[k]);
        ff[f] = fmaxf(a + b1[f], 0.f);
    }
    __syncthreads();
    // ff2 + residual + LN2
    {
        const short* wr = w2T + (size_t)tid * DFF;
        float a = 0.f;
#pragma unroll 8
        for (int f = 0; f < DFF; ++f) a += ff[f] * bf2f(wr[f]);
        t = a + b2[tid] + h1[tid];
    }
    {
        float s = t, sq = t * t;
#pragma unroll
        for (int off = 1; off < 64; off <<= 1) { s += __shfl_xor(s, off); sq += __shfl_xor(sq, off); }
        if (lane == 0) { red[wave][0] = s; red[wave][1] = sq; }
        __syncthreads();
        float ts = red[0][0] + red[1][0] + red[2][0] + red[3][0];
        float tq = red[0][1] + red[1][1] + red[2][1] + red[3][1];
        float mean = ts * (1.f / 256.f);
        float var = fmaxf(tq * (1.f / 256.f) - mean * mean, 0.f);
        float rstd = rsqrtf(var + 1e-5f);
        float y = g2[tid] * (t - mean) * rstd + bt2[tid];
        xpad[(size_t)b * DIM + tid] = f2bf(y);
        if (padrowF) padrowF[(size_t)b * DIM + tid] = y;
    }
}

// ---------- pad-row broadcast ----------
__global__ __launch_bounds__(256) void pad_bcast(const float* __restrict__ padrow,
                                                 float* __restrict__ fout) {
    int b = blockIdx.y;
    int p = blockIdx.x * 4 + (threadIdx.x >> 6);
    if (p >= NPAD) return;
    int d4 = (threadIdx.x & 63) * 4;
    floatx4 v = *(const floatx4*)(padrow + (size_t)b * DIM + d4);
    *(floatx4*)(fout + ((size_t)b * MAXV + p) * DIM + d4) = v;
}

// ---------- V transpose: v [M,256] + padV -> vT [B*H][DH][VST] ----------
__global__ __launch_bounds__(256) void transpose_v(const short* __restrict__ v,
                                                   const short* __restrict__ padV,
                                                   short* __restrict__ vT) {
    __shared__ short lds[32][33];
    int pair = blockIdx.y;
    int b = pair >> 1, h = pair & 1;
    int st = blockIdx.x % 5;              // seq tile: 0..3 real keys, 4 = tail
    int dt = blockIdx.x / 5;              // dh tile 0..3
    int tid = threadIdx.x;
    int sl = tid >> 3, dl = (tid & 7) * 4;
    short4v val;
    if (st < 4) {
        const short* src = v + ((size_t)(b * NV + st * 32 + sl)) * DIM + h * DH + dt * 32 + dl;
        val = *(const short4v*)src;
    } else {
        val = (short4v){0, 0, 0, 0};
        if (sl == 0)
            val = *(const short4v*)(padV + (size_t)b * DIM + h * DH + dt * 32 + dl);
    }
#pragma unroll
    for (int j = 0; j < 4; ++j) lds[sl][dl + j] = val[j];
    __syncthreads();
    int drow = tid >> 3, scol = (tid & 7) * 4;
    short* dst = vT + (size_t)pair * DH * VST + (size_t)(dt * 32 + drow) * VST + st * 32 + scol;
#pragma unroll
    for (int j = 0; j < 4; ++j) dst[j] = lds[scol + j][drow];
}

// ---------- fused attention (packed real rows; pad key as 16-col MFMA tail) ----------
__global__ __launch_bounds__(256) void attn_fused(const short* __restrict__ q,
                                                  const short* __restrict__ k,
                                                  const short* __restrict__ vT,
                                                  const short* __restrict__ padK,
                                                  short* __restrict__ ctx) {
    __shared__ __align__(16) short lA[64 * 32];    //  4 KiB (Q slice)
    __shared__ __align__(16) short lB[128 * 32];   //  8 KiB (K slice / V slice)
    __shared__ __align__(16) short lS[64 * AST];   // 21 KiB weighted exp(S)
    int tid = threadIdx.x;
    int wave = tid >> 6, lane = tid & 63;
    int l15 = lane & 15, quad = lane >> 4;
    int q8 = quad * 8;
    int pair = blockIdx.y;
    int b = pair >> 1, h = pair & 1;
    int m0 = blockIdx.x * 64;             // 0 or 64
    int wm = (wave & 1) * 32;
    int wn = (wave >> 1) * 64;

    int srow = tid >> 2;
    int skoff = (tid & 3) * 8;
    const short* ag = q + (size_t)(b * NV + m0 + srow) * DIM + h * DH + skoff;
    const short* bg = k + (size_t)(b * NV + srow) * DIM + h * DH + skoff;
    const short* kp = padK + (size_t)b * DIM + h * DH + q8;
    short* lA_dst = lA + tid * 8;
    short* lB_dst = lB + tid * 8;
    const float scale = 0.08838834764831845f;  // 1/sqrt(128)

    // zero-fill lS tail cols 144..159 (once; barrier below orders vs readers)
    {
        int zr = tid >> 2, zc = 144 + (tid & 3) * 4;
        *(short4v*)(lS + zr * AST + zc) = (short4v){0, 0, 0, 0};
    }

    floatx4 sacc[2][4];
    floatx4 sacct[2];
#pragma unroll
    for (int i = 0; i < 2; ++i) {
#pragma unroll
        for (int j = 0; j < 4; ++j) sacc[i][j] = (floatx4){0.f, 0.f, 0.f, 0.f};
        sacct[i] = (floatx4){0.f, 0.f, 0.f, 0.f};
    }

    // ---- QK over 128 real keys + 16-col pad tail ----
#pragma unroll
    for (int k0 = 0; k0 < DH; k0 += 32) {
        gload_lds16(ag + k0, lA_dst);
        gload_lds16(bg + k0, lB_dst);
        gload_lds16(bg + (size_t)64 * DIM + k0, lB_dst + 2048);
        __syncthreads();
        short8 aF[2], bF[4];
#pragma unroll
        for (int t = 0; t < 2; ++t)
            aF[t] = *(const short8*)(lA + (wm + t * 16 + l15) * 32 + q8);
#pragma unroll
        for (int t = 0; t < 4; ++t)
            bF[t] = *(const short8*)(lB + (wn + t * 16 + l15) * 32 + q8);
#pragma unroll
        for (int i = 0; i < 2; ++i)
#pragma unroll
            for (int j = 0; j < 4; ++j)
                sacc[i][j] = __builtin_amdgcn_mfma_f32_16x16x32_bf16(aF[i], bF[j], sacc[i][j], 0, 0, 0);
        if (wn == 0) {
            short8 bFt = (l15 == 0) ? *(const short8*)(kp + k0) : (short8){0,0,0,0,0,0,0,0};
#pragma unroll
            for (int i = 0; i < 2; ++i)
                sacct[i] = __builtin_amdgcn_mfma_f32_16x16x32_bf16(aF[i], bFt, sacct[i], 0, 0, 0);
        }
        __syncthreads();
    }
    // ---- exp -> lS (cols 0..127 weight 1; col 128 weight 382; 129..143 weight 0) ----
#pragma unroll
    for (int j = 0; j < 4; ++j) {
        int col = wn + j * 16 + l15;
#pragma unroll
        for (int i = 0; i < 2; ++i) {
#pragma unroll
            for (int r = 0; r < 4; ++r) {
                lS[(wm + i * 16 + quad * 4 + r) * AST + col] =
                    f2bf(__expf(fminf(sacc[i][j][r] * scale, 30.f)));
            }
        }
    }
    if (wn == 0) {
        float wt = (l15 == 0) ? 382.f : 0.f;
#pragma unroll
        for (int i = 0; i < 2; ++i) {
#pragma unroll
            for (int r = 0; r < 4; ++r) {
                lS[(wm + i * 16 + quad * 4 + r) * AST + 128 + l15] =
                    f2bf(wt * __expf(fminf(sacct[i][r] * scale, 30.f)));
            }
        }
    }
    __syncthreads();
    // ---- PV over 160 key-slots (5 ks steps) ----
    const short* vg = vT + (size_t)pair * DH * VST + (size_t)srow * VST + skoff;
    floatx4 oacc[2][4];
#pragma unroll
    for (int i = 0; i < 2; ++i)
#pragma unroll
        for (int j = 0; j < 4; ++j) oacc[i][j] = (floatx4){0.f, 0.f, 0.f, 0.f};
    float rsum[2] = {0.f, 0.f};

#pragma unroll
    for (int ks = 0; ks < 5; ++ks) {
        gload_lds16(vg + ks * 32, lB_dst);
        gload_lds16(vg + (size_t)64 * VST + ks * 32, lB_dst + 2048);
        __syncthreads();
        short8 aP[2], bV[4];
#pragma unroll
        for (int t = 0; t < 2; ++t)
            aP[t] = *(const short8*)(lS + (wm + t * 16 + l15) * AST + ks * 32 + q8);
#pragma unroll
        for (int t = 0; t < 4; ++t)
            bV[t] = *(const short8*)(lB + (wn + t * 16 + l15) * 32 + q8);
#pragma unroll
        for (int i = 0; i < 2; ++i) {
            float s = 0.f;
#pragma unroll
            for (int e = 0; e < 8; ++e) s += bf2f(aP[i][e]);
            rsum[i] += s;
        }
#pragma unroll
        for (int i = 0; i < 2; ++i)
#pragma unroll
            for (int j = 0; j < 4; ++j)
                oacc[i][j] = __builtin_amdgcn_mfma_f32_16x16x32_bf16(aP[i], bV[j], oacc[i][j], 0, 0, 0);
        __syncthreads();
    }

    // ---- epilogue ----
#pragma unroll
    for (int i = 0; i < 2; ++i) {
        rsum[i] += __shfl_xor(rsum[i], 16);
        rsum[i] += __shfl_xor(rsum[i], 32);
    }
    short* outb = ctx + (size_t)(b * NV + m0) * DIM + h * DH;
#pragma unroll
    for (int i = 0; i < 2; ++i) {
#pragma unroll
        for (int r = 0; r < 4; ++r) {
            float inv = 1.f / __shfl(rsum[i], quad * 4 + r);
#pragma unroll
            for (int j = 0; j < 4; ++j) {
                int col = wn + j * 16 + l15;
                int row = wm + i * 16 + quad * 4 + r;
                outb[(size_t)row * DIM + col] = f2bf(oacc[i][j][r] * inv);
            }
        }
    }
}

extern "C" void kernel_launch(void* const* d_in, const int* in_sizes, int n_in,
                              void* d_out, int out_size, void* d_ws, size_t ws_size,
                              hipStream_t stream) {
    const int*   all_codes = (const int*)d_in[0];
    const float* times = (const float*)d_in[3];
    const float* cemb  = (const float*)d_in[4];
    const float* pemb  = (const float*)d_in[5];
    const float* Wq = (const float*)d_in[6];
    const float* Wk = (const float*)d_in[7];
    const float* Wv = (const float*)d_in[8];
    const float* Wo = (const float*)d_in[9];
    const float* bq = (const float*)d_in[10];
    const float* bk = (const float*)d_in[11];
    const float* bv = (const float*)d_in[12];
    const float* bo = (const float*)d_in[13];
    const float* ln1g = (const float*)d_in[14];
    const float* ln1b = (const float*)d_in[15];
    const float* W1 = (const float*)d_in[16];
    const float* b1 = (const float*)d_in[17];
    const float* W2 = (const float*)d_in[18];
    const float* b2 = (const float*)d_in[19];
    const float* ln2g = (const float*)d_in[20];
    const float* ln2b = (const float*)d_in[21];

    char* ws = (char*)d_ws;
    short* wqkvT = (short*)ws;                    // [2][768*256]
    short* woT   = wqkvT + 2 * 196608;            // [2][256*256]
    short* w1T   = woT + 2 * 65536;               // [2][1024*256]
    short* w2T   = w1T + 2 * 262144;              // [2][256*1024]

    char* aux = ws + (3400u << 10);               // past weights (~3.15 MB)
    float* padQ   = (float*)aux;                  // [128][256] f32
    short* padK   = (short*)(aux + 131072);       // [128][256] bf16
    short* padV   = padK + 32768;                 // [128][256] bf16
    short* xpad   = padV + 32768;                 // [128][256] bf16
    float* padrowF = (float*)(aux + 131072 + 3 * 65536);  // [128][256] f32

    const size_t SLOT = (size_t)MROWS * DIM;      // 16384*256 shorts = 8 MiB
    short* xb = (short*)(ws + (4u << 20));
    short* C0 = xb + SLOT;     // q -> h1 (LN1 out)
    short* C1 = C0 + SLOT;     // k
    short* C2 = C1 + SLOT;     // v
    short* C3 = C2 + SLOT;     // ctx
    short* C4 = C3 + SLOT;     // vT [256][128][VST] (10 MiB; last slot, extends into free ws)

    wtrans_all<<<dim3(1024, 12), 256, 0, stream>>>(Wq, Wk, Wv, Wo, W1, W2,
                                                   wqkvT, woT, w1T, w2T);
    build_x<<<MROWS, 256, 0, stream>>>(all_codes, times, cemb, xb);
    build_xpad<<<BATCH, 256, 0, stream>>>(pemb, xpad);

    for (int l = 0; l < NLAYERS; ++l) {
        const short* qkv_l = wqkvT + (size_t)l * 196608;
        const short* wo_l = woT + (size_t)l * 65536;
        const short* w1_l = w1T + (size_t)l * 262144;
        const short* w2_l = w2T + (size_t)l * 262144;
        int last = (l == NLAYERS - 1);

        gemm_qkv<<<dim3(6, MROWS / 128), 256, 0, stream>>>(xb, qkv_l, bq + l * 256, bk + l * 256,
                                                           bv + l * 256, C0, C1, C2);
        pad_qkv<<<BATCH, 256, 0, stream>>>(xpad, qkv_l, bq + l * 256, bk + l * 256,
                                           bv + l * 256, padQ, padK, padV);
        transpose_v<<<dim3(20, BATCH * NH), 256, 0, stream>>>(C2, padV, C4);
        attn_fused<<<dim3(2, BATCH * NH), 256, 0, stream>>>(C0, C1, C4, padK, C3);
        // h1 = LN1(x + ctx@Wo + bo): reads C3 + xb, writes C0.
        gemm_wo_ln<<<MROWS / 64, 256, 0, stream>>>(C3, wo_l, bo + l * 256, xb,
                                                   ln1g + l * 256, ln1b + l * 256, C0);
        // x = LN2(h1 + ffn(h1)): reads C0, writes xb (or f32 fout on last layer).
        ff_fused<<<MROWS / 64, 256, 0, stream>>>(C0, w1_l, b1 + l * 1024, w2_l, b2 + l * 256,
                                                 ln2g + l * 256, ln2b + l * 256, xb,
                                                 last ? (float*)d_out : nullptr);
        // pad-row side path for this layer (reads this layer's k/v before they're overwritten)
        pad_tail<<<BATCH, 256, 0, stream>>>(padQ, padK, padV, C1, C2,
                                            wo_l, bo + l * 256, ln1g + l * 256, ln1b + l * 256,
                                            w1_l, b1 + l * 1024, w2_l, b2 + l * 256,
                                            ln2g + l * 256, ln2b + l * 256,
                                            xpad, last ? padrowF : nullptr);
        if (last)
            pad_bcast<<<dim3(96, BATCH), 256, 0, stream>>>(padrowF, (float*)d_out);
    }
}

// Round 9
// 415.673 us; speedup vs baseline: 1.7353x; 1.2984x over previous
//
#include <hip/hip_runtime.h>
#include <cstddef>

// ---------- constants ----------
#define BATCH 128
#define NV 128          // real visits per person
#define CPV 16
#define MAXV 510
#define NPAD 382        // identical pad rows represented by one appended row per batch
#define DIM 256
#define NH 2
#define DH 128
#define NLAYERS 2
#define DFF 1024
#define RROWS (BATCH * NV)       // 16384 real rows (row = b*128 + r)
#define M2 (RROWS + BATCH)       // 16512 = 129*128: + one pad row per batch at RROWS+b
#define AST 168                  // lS row stride
#define VST 160                  // vT seq stride (128 keys + 32-tail)

typedef __attribute__((ext_vector_type(8))) short short8;
typedef __attribute__((ext_vector_type(4))) short short4v;
typedef __attribute__((ext_vector_type(4))) float floatx4;

__device__ __forceinline__ short f2bf(float f) {
    union { float f; unsigned u; } v; v.f = f;
    unsigned r = v.u + 0x7fffu + ((v.u >> 16) & 1u);
    return (short)(r >> 16);
}
__device__ __forceinline__ float bf2f(short s) {
    union { unsigned u; float f; } v; v.u = ((unsigned)(unsigned short)s) << 16;
    return v.f;
}

__device__ __forceinline__ void gload_lds16(const short* g, short* l) {
    __builtin_amdgcn_global_load_lds(
        (const __attribute__((address_space(1))) unsigned int*)g,
        (__attribute__((address_space(3))) unsigned int*)l,
        16, 0, 0);
}

// ---------- all weight transposes in ONE launch ----------
__global__ __launch_bounds__(256) void wtrans_all(const float* __restrict__ Wq,
                                                  const float* __restrict__ Wk,
                                                  const float* __restrict__ Wv,
                                                  const float* __restrict__ Wo,
                                                  const float* __restrict__ W1,
                                                  const float* __restrict__ W2,
                                                  short* __restrict__ wqkvT,
                                                  short* __restrict__ woT,
                                                  short* __restrict__ w1T,
                                                  short* __restrict__ w2T) {
    int y = blockIdx.y;
    int l = y / 6, w = y - l * 6;
    const float* src; short* dst; int K, nsh;
    switch (w) {
        case 0:  src = Wq + (size_t)l * 65536;  dst = wqkvT + (size_t)l * 196608;           K = 256;  nsh = 8;  break;
        case 1:  src = Wk + (size_t)l * 65536;  dst = wqkvT + (size_t)l * 196608 + 65536;   K = 256;  nsh = 8;  break;
        case 2:  src = Wv + (size_t)l * 65536;  dst = wqkvT + (size_t)l * 196608 + 131072;  K = 256;  nsh = 8;  break;
        case 3:  src = Wo + (size_t)l * 65536;  dst = woT   + (size_t)l * 65536;            K = 256;  nsh = 8;  break;
        case 4:  src = W1 + (size_t)l * 262144; dst = w1T   + (size_t)l * 262144;           K = 256;  nsh = 10; break;
        default: src = W2 + (size_t)l * 262144; dst = w2T   + (size_t)l * 262144;           K = 1024; nsh = 8;  break;
    }
    int N = 1 << nsh;
    int idx = blockIdx.x * 256 + threadIdx.x;
    if (idx >= K * N) return;
    int k = idx >> nsh, n = idx & (N - 1);
    dst[(size_t)n * K + k] = f2bf(src[idx]);
}

// ---------- build x: 16384 real rows + 128 pad rows (= pad_emb) ----------
__global__ __launch_bounds__(256) void build_x(const int* __restrict__ codes,
                                               const float* __restrict__ times,
                                               const float* __restrict__ cemb,
                                               const float* __restrict__ pemb,
                                               short* __restrict__ x) {
    int row = blockIdx.x;
    int d = threadIdx.x;
    float val;
    if (row >= RROWS) {
        val = pemb[d];
    } else {
        int b = row >> 7;
        int r = row & 127;
        int visit = b * NV + r;
        const int* cb = codes + visit * CPV;
        float s = 0.f;
#pragma unroll
        for (int c = 0; c < CPV; ++c)
            s += cemb[(size_t)cb[c] * DIM + d];
        float t = times[visit];
        t = fminf(fmaxf(t, 0.f), 364.f);
        int i = d & 127;
        float ang = t * expf(-0.03597789207803197f * (float)i);
        float te = (d < 128) ? sinf(ang) : cosf(ang);
        val = s + te;
    }
    x[(size_t)row * DIM + d] = f2bf(val);
}

// ---------- merged QKV GEMM (2-phase dbuf): BT = [WqT; WkT; WvT] ----------
__global__ __launch_bounds__(256) void gemm_qkv(const short* __restrict__ A,
                                                const short* __restrict__ BT,
                                                const float* __restrict__ bq,
                                                const float* __restrict__ bk,
                                                const float* __restrict__ bv,
                                                short* __restrict__ qo,
                                                short* __restrict__ ko,
                                                short* __restrict__ vo) {
    __shared__ __align__(16) short lA[2][128 * 32];
    __shared__ __align__(16) short lB[2][128 * 32];
    int tid = threadIdx.x;
    int wave = tid >> 6, lane = tid & 63;
    int l15 = lane & 15, quad = lane >> 4;
    int q8 = quad * 8;
    int m0 = blockIdx.y * 128;
    int n0 = blockIdx.x * 128;
    int sel = blockIdx.x >> 1;
    int nloc = n0 & 255;
    int wm = (wave & 1) * 64;
    int wn = (wave >> 1) * 64;

    int srow = tid >> 2;
    int skoff = (tid & 3) * 8;
    const short* ag = A + (size_t)(m0 + srow) * DIM + skoff;
    const short* bg = BT + (size_t)(n0 + srow) * DIM + skoff;
    const size_t rstep = (size_t)64 * DIM;
    int t8 = tid * 8;

    floatx4 acc[4][4];
#pragma unroll
    for (int i = 0; i < 4; ++i)
#pragma unroll
        for (int j = 0; j < 4; ++j) acc[i][j] = (floatx4){0.f, 0.f, 0.f, 0.f};

    gload_lds16(ag, lA[0] + t8);
    gload_lds16(ag + rstep, lA[0] + 2048 + t8);
    gload_lds16(bg, lB[0] + t8);
    gload_lds16(bg + rstep, lB[0] + 2048 + t8);
    __syncthreads();
    int cur = 0;
#pragma unroll
    for (int k0 = 0; k0 < 8; ++k0) {
        if (k0 < 7) {
            int kn = (k0 + 1) * 32;
            gload_lds16(ag + kn, lA[cur ^ 1] + t8);
            gload_lds16(ag + rstep + kn, lA[cur ^ 1] + 2048 + t8);
            gload_lds16(bg + kn, lB[cur ^ 1] + t8);
            gload_lds16(bg + rstep + kn, lB[cur ^ 1] + 2048 + t8);
        }
        short8 aF[4], bF[4];
#pragma unroll
        for (int t = 0; t < 4; ++t) {
            aF[t] = *(const short8*)(lA[cur] + (wm + t * 16 + l15) * 32 + q8);
            bF[t] = *(const short8*)(lB[cur] + (wn + t * 16 + l15) * 32 + q8);
        }
#pragma unroll
        for (int i = 0; i < 4; ++i)
#pragma unroll
            for (int j = 0; j < 4; ++j)
                acc[i][j] = __builtin_amdgcn_mfma_f32_16x16x32_bf16(aF[i], bF[j], acc[i][j], 0, 0, 0);
        __syncthreads();
        cur ^= 1;
    }

    const float* bias = (sel == 0) ? bq : (sel == 1) ? bk : bv;
    short* out = (sel == 0) ? qo : (sel == 1) ? ko : vo;
#pragma unroll
    for (int j = 0; j < 4; ++j) {
        int col = nloc + wn + j * 16 + l15;
        float bval = bias[col];
#pragma unroll
        for (int i = 0; i < 4; ++i) {
#pragma unroll
            for (int r = 0; r < 4; ++r) {
                int row = m0 + wm + i * 16 + quad * 4 + r;
                out[(size_t)row * DIM + col] = f2bf(acc[i][j][r] + bval);
            }
        }
    }
}

// ---------- Wo projection + residual + LN1 (2-phase dbuf).  BM=64. ----------
__global__ __launch_bounds__(256) void gemm_wo_ln(const short* __restrict__ CTX,
                                                  const short* __restrict__ WoT,
                                                  const float* __restrict__ bo,
                                                  const short* __restrict__ X,
                                                  const float* __restrict__ g,
                                                  const float* __restrict__ bta,
                                                  short* __restrict__ xout) {
    __shared__ __align__(16) short lA[2][64 * 32];
    __shared__ __align__(16) short lB[2][256 * 32];
    int tid = threadIdx.x;
    int wave = tid >> 6, lane = tid & 63;
    int l15 = lane & 15, quad = lane >> 4;
    int q8 = quad * 8;
    int m0 = blockIdx.x * 64;
    int wr = wave * 16;
    int srow = tid >> 2;
    int skoff = (tid & 3) * 8;
    const short* ag = CTX + (size_t)(m0 + srow) * DIM + skoff;
    const short* bg = WoT + (size_t)srow * DIM + skoff;
    int t8 = tid * 8;

    floatx4 acc[16];
#pragma unroll
    for (int j = 0; j < 16; ++j) acc[j] = (floatx4){0.f, 0.f, 0.f, 0.f};

    gload_lds16(ag, lA[0] + t8);
    gload_lds16(bg, lB[0] + t8);
    gload_lds16(bg + (size_t)64 * DIM, lB[0] + 2048 + t8);
    gload_lds16(bg + (size_t)128 * DIM, lB[0] + 4096 + t8);
    gload_lds16(bg + (size_t)192 * DIM, lB[0] + 6144 + t8);
    __syncthreads();
    int cur = 0;
#pragma unroll
    for (int k0 = 0; k0 < 8; ++k0) {
        if (k0 < 7) {
            int kn = (k0 + 1) * 32;
            gload_lds16(ag + kn, lA[cur ^ 1] + t8);
            gload_lds16(bg + kn, lB[cur ^ 1] + t8);
            gload_lds16(bg + (size_t)64 * DIM + kn, lB[cur ^ 1] + 2048 + t8);
            gload_lds16(bg + (size_t)128 * DIM + kn, lB[cur ^ 1] + 4096 + t8);
            gload_lds16(bg + (size_t)192 * DIM + kn, lB[cur ^ 1] + 6144 + t8);
        }
        short8 aF = *(const short8*)(lA[cur] + (wr + l15) * 32 + q8);
#pragma unroll
        for (int j = 0; j < 16; ++j) {
            short8 bF = *(const short8*)(lB[cur] + (j * 16 + l15) * 32 + q8);
            acc[j] = __builtin_amdgcn_mfma_f32_16x16x32_bf16(aF, bF, acc[j], 0, 0, 0);
        }
        __syncthreads();
        cur ^= 1;
    }

    float bias[16], gam[16], bet[16];
#pragma unroll
    for (int j = 0; j < 16; ++j) {
        int col = j * 16 + l15;
        bias[j] = bo[col]; gam[j] = g[col]; bet[j] = bta[col];
    }
#pragma unroll
    for (int r = 0; r < 4; ++r) {
        int row = m0 + wr + quad * 4 + r;
        float v[16], s = 0.f, sq = 0.f;
#pragma unroll
        for (int j = 0; j < 16; ++j) {
            v[j] = acc[j][r] + bias[j] + bf2f(X[(size_t)row * DIM + j * 16 + l15]);
            s += v[j]; sq += v[j] * v[j];
        }
        s += __shfl_xor(s, 1); sq += __shfl_xor(sq, 1);
        s += __shfl_xor(s, 2); sq += __shfl_xor(sq, 2);
        s += __shfl_xor(s, 4); sq += __shfl_xor(sq, 4);
        s += __shfl_xor(s, 8); sq += __shfl_xor(sq, 8);
        float mean = s * (1.f / 256.f);
        float var = fmaxf(sq * (1.f / 256.f) - mean * mean, 0.f);
        float rstd = rsqrtf(var + 1e-5f);
#pragma unroll
        for (int j = 0; j < 16; ++j) {
            float y = gam[j] * (v[j] - mean) * rstd + bet[j];
            xout[(size_t)row * DIM + j * 16 + l15] = f2bf(y);
        }
    }
}

// ---------- fused FFN + LN2 (2-phase dbuf), BM=64 ----------
#define PST 136
__global__ __launch_bounds__(256, 2) void ff_fused(const short* __restrict__ X,
                                                   const short* __restrict__ W1T,
                                                   const float* __restrict__ b1,
                                                   const short* __restrict__ W2T,
                                                   const float* __restrict__ b2,
                                                   const float* __restrict__ g2,
                                                   const float* __restrict__ bt2,
                                                   short* __restrict__ xout,
                                                   float* __restrict__ fout,
                                                   float* __restrict__ padrowF) {
    __shared__ __align__(16) short lA[2][64 * 32];
    __shared__ __align__(16) short lB[2][128 * 32];
    __shared__ __align__(16) short lB2[2][256 * 32];
    __shared__ __align__(16) short lP[64 * PST];
    __shared__ float redS[4][32], redQ[4][32];
    int tid = threadIdx.x;
    int wave = tid >> 6, lane = tid & 63;
    int l15 = lane & 15, quad = lane >> 4;
    int q8 = quad * 8;
    int m0 = blockIdx.x * 64;
    int wm = (wave & 1) * 32;
    int wf = (wave >> 1) * 64;
    int wn2 = (wave >> 1) * 128;
    int srow = tid >> 2;
    int spart = (tid & 3) * 8;
    const short* xg = X + (size_t)(m0 + srow) * DIM + spart;
    int t8 = tid * 8;

    floatx4 acc2[2][8];
#pragma unroll
    for (int i = 0; i < 2; ++i)
#pragma unroll
        for (int j = 0; j < 8; ++j) acc2[i][j] = (floatx4){0.f, 0.f, 0.f, 0.f};

    for (int f0 = 0; f0 < DFF; f0 += 128) {
        const short* w1g = W1T + (size_t)(f0 + srow) * DIM + spart;
        floatx4 acc1[2][4];
#pragma unroll
        for (int i = 0; i < 2; ++i)
#pragma unroll
            for (int j = 0; j < 4; ++j) acc1[i][j] = (floatx4){0.f, 0.f, 0.f, 0.f};

        gload_lds16(xg, lA[0] + t8);
        gload_lds16(w1g, lB[0] + t8);
        gload_lds16(w1g + (size_t)64 * DIM, lB[0] + 2048 + t8);
        __syncthreads();
        int cur = 0;
#pragma unroll
        for (int k0 = 0; k0 < 8; ++k0) {
            if (k0 < 7) {
                int kn = (k0 + 1) * 32;
                gload_lds16(xg + kn, lA[cur ^ 1] + t8);
                gload_lds16(w1g + kn, lB[cur ^ 1] + t8);
                gload_lds16(w1g + (size_t)64 * DIM + kn, lB[cur ^ 1] + 2048 + t8);
            }
            short8 aF[2], bF[4];
#pragma unroll
            for (int t = 0; t < 2; ++t)
                aF[t] = *(const short8*)(lA[cur] + (wm + t * 16 + l15) * 32 + q8);
#pragma unroll
            for (int t = 0; t < 4; ++t)
                bF[t] = *(const short8*)(lB[cur] + (wf + t * 16 + l15) * 32 + q8);
#pragma unroll
            for (int i = 0; i < 2; ++i)
#pragma unroll
                for (int j = 0; j < 4; ++j)
                    acc1[i][j] = __builtin_amdgcn_mfma_f32_16x16x32_bf16(aF[i], bF[j], acc1[i][j], 0, 0, 0);
            __syncthreads();
            cur ^= 1;
        }

        {
            const short* w2g = W2T + (size_t)srow * DFF + f0 + spart;
            gload_lds16(w2g, lB2[0] + t8);
            gload_lds16(w2g + (size_t)64 * DFF, lB2[0] + 2048 + t8);
            gload_lds16(w2g + (size_t)128 * DFF, lB2[0] + 4096 + t8);
            gload_lds16(w2g + (size_t)192 * DFF, lB2[0] + 6144 + t8);
        }
#pragma unroll
        for (int j = 0; j < 4; ++j) {
            int fc = wf + j * 16 + l15;
            float bval = b1[f0 + fc];
#pragma unroll
            for (int i = 0; i < 2; ++i) {
#pragma unroll
                for (int r = 0; r < 4; ++r) {
                    float v = acc1[i][j][r] + bval;
                    lP[(wm + i * 16 + quad * 4 + r) * PST + fc] = f2bf(fmaxf(v, 0.f));
                }
            }
        }
        __syncthreads();
        cur = 0;
#pragma unroll
        for (int ks = 0; ks < 4; ++ks) {
            if (ks < 3) {
                const short* w2g = W2T + (size_t)srow * DFF + f0 + (ks + 1) * 32 + spart;
                gload_lds16(w2g, lB2[cur ^ 1] + t8);
                gload_lds16(w2g + (size_t)64 * DFF, lB2[cur ^ 1] + 2048 + t8);
                gload_lds16(w2g + (size_t)128 * DFF, lB2[cur ^ 1] + 4096 + t8);
                gload_lds16(w2g + (size_t)192 * DFF, lB2[cur ^ 1] + 6144 + t8);
            }
            short8 aP[2], bW[8];
#pragma unroll
            for (int t = 0; t < 2; ++t)
                aP[t] = *(const short8*)(lP + (wm + t * 16 + l15) * PST + ks * 32 + q8);
#pragma unroll
            for (int j = 0; j < 8; ++j)
                bW[j] = *(const short8*)(lB2[cur] + (wn2 + j * 16 + l15) * 32 + q8);
#pragma unroll
            for (int i = 0; i < 2; ++i)
#pragma unroll
                for (int j = 0; j < 8; ++j)
                    acc2[i][j] = __builtin_amdgcn_mfma_f32_16x16x32_bf16(aP[i], bW[j], acc2[i][j], 0, 0, 0);
            __syncthreads();
            cur ^= 1;
        }
    }

    // ---- epilogue: residual + bias, LN2 over full row ----
    float b2v[8];
#pragma unroll
    for (int j = 0; j < 8; ++j) b2v[j] = b2[wn2 + j * 16 + l15];
#pragma unroll
    for (int i = 0; i < 2; ++i) {
#pragma unroll
        for (int r = 0; r < 4; ++r) {
            int row = m0 + wm + i * 16 + quad * 4 + r;
            float s = 0.f, sq = 0.f;
#pragma unroll
            for (int j = 0; j < 8; ++j) {
                float v = acc2[i][j][r] + b2v[j] + bf2f(X[(size_t)row * DIM + wn2 + j * 16 + l15]);
                acc2[i][j][r] = v;
                s += v; sq += v * v;
            }
            s += __shfl_xor(s, 1); sq += __shfl_xor(sq, 1);
            s += __shfl_xor(s, 2); sq += __shfl_xor(sq, 2);
            s += __shfl_xor(s, 4); sq += __shfl_xor(sq, 4);
            s += __shfl_xor(s, 8); sq += __shfl_xor(sq, 8);
            if (l15 == 0) {
                int idx = i * 16 + quad * 4 + r;
                redS[wave][idx] = s;
                redQ[wave][idx] = sq;
            }
        }
    }
    __syncthreads();
    float gam[8], bet[8];
#pragma unroll
    for (int j = 0; j < 8; ++j) {
        int col = wn2 + j * 16 + l15;
        gam[j] = g2[col]; bet[j] = bt2[col];
    }
#pragma unroll
    for (int i = 0; i < 2; ++i) {
#pragma unroll
        for (int r = 0; r < 4; ++r) {
            int idx = i * 16 + quad * 4 + r;
            float ts = redS[wave][idx] + redS[wave ^ 2][idx];
            float tq = redQ[wave][idx] + redQ[wave ^ 2][idx];
            float mean = ts * (1.f / 256.f);
            float var = fmaxf(tq * (1.f / 256.f) - mean * mean, 0.f);
            float rstd = rsqrtf(var + 1e-5f);
            int grow = m0 + wm + i * 16 + quad * 4 + r;
            if (!fout) {
#pragma unroll
                for (int j = 0; j < 8; ++j) {
                    float y = gam[j] * (acc2[i][j][r] - mean) * rstd + bet[j];
                    xout[(size_t)grow * DIM + wn2 + j * 16 + l15] = f2bf(y);
                }
            } else if (grow < RROWS) {
                int bb = grow >> 7, rr = grow & 127;
                float* dst = fout + ((size_t)bb * MAXV + NPAD + rr) * DIM;
#pragma unroll
                for (int j = 0; j < 8; ++j) {
                    float y = gam[j] * (acc2[i][j][r] - mean) * rstd + bet[j];
                    dst[wn2 + j * 16 + l15] = y;
                }
            } else {
                float* dst = padrowF + (size_t)(grow - RROWS) * DIM;
#pragma unroll
                for (int j = 0; j < 8; ++j) {
                    float y = gam[j] * (acc2[i][j][r] - mean) * rstd + bet[j];
                    dst[wn2 + j * 16 + l15] = y;
                }
            }
        }
    }
}

// ---------- pad-query attention: ctx row RROWS+b from 128 real keys + pad key ----------
__global__ __launch_bounds__(256) void pad_attn(const short* __restrict__ q,
                                                const short* __restrict__ k,
                                                const short* __restrict__ v,
                                                short* __restrict__ ctx) {
    __shared__ float qv[256], wgt[2][128], wp[2], den[2];
    int b = blockIdx.x, tid = threadIdx.x;
    int h = tid >> 7, kk = tid & 127;
    const float scale = 0.08838834764831845f;
    qv[tid] = bf2f(q[(size_t)(RROWS + b) * DIM + tid]);
    __syncthreads();
    // score vs real key kk (vectorized row read)
    {
        const short8* krow = (const short8*)(k + (size_t)(b * NV + kk) * DIM + h * DH);
        float s = 0.f;
#pragma unroll
        for (int c = 0; c < 16; ++c) {
            short8 k8 = krow[c];
#pragma unroll
            for (int e = 0; e < 8; ++e) s += bf2f(k8[e]) * qv[h * DH + c * 8 + e];
        }
        wgt[h][kk] = __expf(fminf(s * scale, 30.f));
    }
    // score vs pad key, weight 382
    if (kk == 0) {
        const short8* kp = (const short8*)(k + (size_t)(RROWS + b) * DIM + h * DH);
        float sp = 0.f;
#pragma unroll
        for (int c = 0; c < 16; ++c) {
            short8 k8 = kp[c];
#pragma unroll
            for (int e = 0; e < 8; ++e) sp += bf2f(k8[e]) * qv[h * DH + c * 8 + e];
        }
        wp[h] = 382.f * __expf(fminf(sp * scale, 30.f));
    }
    __syncthreads();
    if (kk == 0) {
        float d = wp[h];
        for (int i = 0; i < 128; ++i) d += wgt[h][i];
        den[h] = d;
    }
    __syncthreads();
    // ctx: output dim tid = h*DH + kk
    {
        const short* vcol = v + (size_t)(b * NV) * DIM + h * DH + kk;
        float c = 0.f;
#pragma unroll 8
        for (int key = 0; key < 128; ++key) c += wgt[h][key] * bf2f(vcol[(size_t)key * DIM]);
        c += wp[h] * bf2f(v[(size_t)(RROWS + b) * DIM + h * DH + kk]);
        ctx[(size_t)(RROWS + b) * DIM + tid] = f2bf(c / den[h]);
    }
}

// ---------- pad-row broadcast ----------
__global__ __launch_bounds__(256) void pad_bcast(const float* __restrict__ padrow,
                                                 float* __restrict__ fout) {
    int b = blockIdx.y;
    int p = blockIdx.x * 4 + (threadIdx.x >> 6);
    if (p >= NPAD) return;
    int d4 = (threadIdx.x & 63) * 4;
    floatx4 v = *(const floatx4*)(padrow + (size_t)b * DIM + d4);
    *(floatx4*)(fout + ((size_t)b * MAXV + p) * DIM + d4) = v;
}

// ---------- V transpose: v rows [b*NV .. b*NV+127] + pad row RROWS+b -> vT [B*H][DH][VST] ----------
__global__ __launch_bounds__(256) void transpose_v(const short* __restrict__ v,
                                                   short* __restrict__ vT) {
    __shared__ short lds[32][33];
    int pair = blockIdx.y;
    int b = pair >> 1, h = pair & 1;
    int st = blockIdx.x % 5;              // seq tile: 0..3 real keys, 4 = tail
    int dt = blockIdx.x / 5;              // dh tile 0..3
    int tid = threadIdx.x;
    int sl = tid >> 3, dl = (tid & 7) * 4;
    short4v val;
    if (st < 4) {
        const short* src = v + ((size_t)(b * NV + st * 32 + sl)) * DIM + h * DH + dt * 32 + dl;
        val = *(const short4v*)src;
    } else {
        val = (short4v){0, 0, 0, 0};
        if (sl == 0)
            val = *(const short4v*)(v + (size_t)(RROWS + b) * DIM + h * DH + dt * 32 + dl);
    }
#pragma unroll
    for (int j = 0; j < 4; ++j) lds[sl][dl + j] = val[j];
    __syncthreads();
    int drow = tid >> 3, scol = (tid & 7) * 4;
    short* dst = vT + (size_t)pair * DH * VST + (size_t)(dt * 32 + drow) * VST + st * 32 + scol;
#pragma unroll
    for (int j = 0; j < 4; ++j) dst[j] = lds[scol + j][drow];
}

// ---------- fused attention (real-query rows; pad key as 16-col MFMA tail) ----------
__global__ __launch_bounds__(256) void attn_fused(const short* __restrict__ q,
                                                  const short* __restrict__ k,
                                                  const short* __restrict__ vT,
                                                  short* __restrict__ ctx) {
    __shared__ __align__(16) short lA[64 * 32];    //  4 KiB (Q slice)
    __shared__ __align__(16) short lB[128 * 32];   //  8 KiB (K slice / V slice)
    __shared__ __align__(16) short lS[64 * AST];   // 21 KiB weighted exp(S)
    int tid = threadIdx.x;
    int wave = tid >> 6, lane = tid & 63;
    int l15 = lane & 15, quad = lane >> 4;
    int q8 = quad * 8;
    int pair = blockIdx.y;
    int b = pair >> 1, h = pair & 1;
    int m0 = blockIdx.x * 64;             // 0 or 64
    int wm = (wave & 1) * 32;
    int wn = (wave >> 1) * 64;

    int srow = tid >> 2;
    int skoff = (tid & 3) * 8;
    const short* ag = q + (size_t)(b * NV + m0 + srow) * DIM + h * DH + skoff;
    const short* bg = k + (size_t)(b * NV + srow) * DIM + h * DH + skoff;
    const short* kp = k + (size_t)(RROWS + b) * DIM + h * DH + q8;
    short* lA_dst = lA + tid * 8;
    short* lB_dst = lB + tid * 8;
    const float scale = 0.08838834764831845f;  // 1/sqrt(128)

    // zero-fill lS tail cols 144..159 (once; barriers below order vs readers)
    {
        int zr = tid >> 2, zc = 144 + (tid & 3) * 4;
        *(short4v*)(lS + zr * AST + zc) = (short4v){0, 0, 0, 0};
    }

    floatx4 sacc[2][4];
    floatx4 sacct[2];
#pragma unroll
    for (int i = 0; i < 2; ++i) {
#pragma unroll
        for (int j = 0; j < 4; ++j) sacc[i][j] = (floatx4){0.f, 0.f, 0.f, 0.f};
        sacct[i] = (floatx4){0.f, 0.f, 0.f, 0.f};
    }

    // ---- QK over 128 real keys + 16-col pad tail ----
#pragma unroll
    for (int k0 = 0; k0 < DH; k0 += 32) {
        gload_lds16(ag + k0, lA_dst);
        gload_lds16(bg + k0, lB_dst);
        gload_lds16(bg + (size_t)64 * DIM + k0, lB_dst + 2048);
        __syncthreads();
        short8 aF[2], bF[4];
#pragma unroll
        for (int t = 0; t < 2; ++t)
            aF[t] = *(const short8*)(lA + (wm + t * 16 + l15) * 32 + q8);
#pragma unroll
        for (int t = 0; t < 4; ++t)
            bF[t] = *(const short8*)(lB + (wn + t * 16 + l15) * 32 + q8);
#pragma unroll
        for (int i = 0; i < 2; ++i)
#pragma unroll
            for (int j = 0; j < 4; ++j)
                sacc[i][j] = __builtin_amdgcn_mfma_f32_16x16x32_bf16(aF[i], bF[j], sacc[i][j], 0, 0, 0);
        if (wn == 0) {
            short8 bFt = (l15 == 0) ? *(const short8*)(kp + k0) : (short8){0,0,0,0,0,0,0,0};
#pragma unroll
            for (int i = 0; i < 2; ++i)
                sacct[i] = __builtin_amdgcn_mfma_f32_16x16x32_bf16(aF[i], bFt, sacct[i], 0, 0, 0);
        }
        __syncthreads();
    }
    // ---- exp -> lS (cols 0..127 weight 1; col 128 weight 382; 129..143 weight 0) ----
#pragma unroll
    for (int j = 0; j < 4; ++j) {
        int col = wn + j * 16 + l15;
#pragma unroll
        for (int i = 0; i < 2; ++i) {
#pragma unroll
            for (int r = 0; r < 4; ++r) {
                lS[(wm + i * 16 + quad * 4 + r) * AST + col] =
                    f2bf(__expf(fminf(sacc[i][j][r] * scale, 30.f)));
            }
        }
    }
    if (wn == 0) {
        float wt = (l15 == 0) ? 382.f : 0.f;
#pragma unroll
        for (int i = 0; i < 2; ++i) {
#pragma unroll
            for (int r = 0; r < 4; ++r) {
                lS[(wm + i * 16 + quad * 4 + r) * AST + 128 + l15] =
                    f2bf(wt * __expf(fminf(sacct[i][r] * scale, 30.f)));
            }
        }
    }
    __syncthreads();
    // ---- PV over 160 key-slots (5 ks steps) ----
    const short* vg = vT + (size_t)pair * DH * VST + (size_t)srow * VST + skoff;
    floatx4 oacc[2][4];
#pragma unroll
    for (int i = 0; i < 2; ++i)
#pragma unroll
        for (int j = 0; j < 4; ++j) oacc[i][j] = (floatx4){0.f, 0.f, 0.f, 0.f};
    float rsum[2] = {0.f, 0.f};

#pragma unroll
    for (int ks = 0; ks < 5; ++ks) {
        gload_lds16(vg + ks * 32, lB_dst);
        gload_lds16(vg + (size_t)64 * VST + ks * 32, lB_dst + 2048);
        __syncthreads();
        short8 aP[2], bV[4];
#pragma unroll
        for (int t = 0; t < 2; ++t)
            aP[t] = *(const short8*)(lS + (wm + t * 16 + l15) * AST + ks * 32 + q8);
#pragma unroll
        for (int t = 0; t < 4; ++t)
            bV[t] = *(const short8*)(lB + (wn + t * 16 + l15) * 32 + q8);
#pragma unroll
        for (int i = 0; i < 2; ++i) {
            float s = 0.f;
#pragma unroll
            for (int e = 0; e < 8; ++e) s += bf2f(aP[i][e]);
            rsum[i] += s;
        }
#pragma unroll
        for (int i = 0; i < 2; ++i)
#pragma unroll
            for (int j = 0; j < 4; ++j)
                oacc[i][j] = __builtin_amdgcn_mfma_f32_16x16x32_bf16(aP[i], bV[j], oacc[i][j], 0, 0, 0);
        __syncthreads();
    }

    // ---- epilogue ----
#pragma unroll
    for (int i = 0; i < 2; ++i) {
        rsum[i] += __shfl_xor(rsum[i], 16);
        rsum[i] += __shfl_xor(rsum[i], 32);
    }
    short* outb = ctx + (size_t)(b * NV + m0) * DIM + h * DH;
#pragma unroll
    for (int i = 0; i < 2; ++i) {
#pragma unroll
        for (int r = 0; r < 4; ++r) {
            float inv = 1.f / __shfl(rsum[i], quad * 4 + r);
#pragma unroll
            for (int j = 0; j < 4; ++j) {
                int col = wn + j * 16 + l15;
                int row = wm + i * 16 + quad * 4 + r;
                outb[(size_t)row * DIM + col] = f2bf(oacc[i][j][r] * inv);
            }
        }
    }
}

extern "C" void kernel_launch(void* const* d_in, const int* in_sizes, int n_in,
                              void* d_out, int out_size, void* d_ws, size_t ws_size,
                              hipStream_t stream) {
    const int*   all_codes = (const int*)d_in[0];
    const float* times = (const float*)d_in[3];
    const float* cemb  = (const float*)d_in[4];
    const float* pemb  = (const float*)d_in[5];
    const float* Wq = (const float*)d_in[6];
    const float* Wk = (const float*)d_in[7];
    const float* Wv = (const float*)d_in[8];
    const float* Wo = (const float*)d_in[9];
    const float* bq = (const float*)d_in[10];
    const float* bk = (const float*)d_in[11];
    const float* bv = (const float*)d_in[12];
    const float* bo = (const float*)d_in[13];
    const float* ln1g = (const float*)d_in[14];
    const float* ln1b = (const float*)d_in[15];
    const float* W1 = (const float*)d_in[16];
    const float* b1 = (const float*)d_in[17];
    const float* W2 = (const float*)d_in[18];
    const float* b2 = (const float*)d_in[19];
    const float* ln2g = (const float*)d_in[20];
    const float* ln2b = (const float*)d_in[21];

    char* ws = (char*)d_ws;
    short* wqkvT = (short*)ws;                    // [2][768*256]
    short* woT   = wqkvT + 2 * 196608;            // [2][256*256]
    short* w1T   = woT + 2 * 65536;               // [2][1024*256]
    short* w2T   = w1T + 2 * 262144;              // [2][256*1024]
    float* padrowF = (float*)(ws + (3500u << 10));// [128][256] f32 (128 KiB)

    const size_t SLOT = (size_t)M2 * DIM;         // 16512*256 shorts = 8.25 MiB
    short* xb = (short*)(ws + (4u << 20));
    short* C0 = xb + SLOT;     // q -> h1 (LN1 out)
    short* C1 = C0 + SLOT;     // k
    short* C2 = C1 + SLOT;     // v
    short* C3 = C2 + SLOT;     // ctx
    short* C4 = C3 + SLOT;     // vT [256][128][VST] (10.5 MiB; last slot)

    wtrans_all<<<dim3(1024, 12), 256, 0, stream>>>(Wq, Wk, Wv, Wo, W1, W2,
                                                   wqkvT, woT, w1T, w2T);
    build_x<<<M2, 256, 0, stream>>>(all_codes, times, cemb, pemb, xb);

    for (int l = 0; l < NLAYERS; ++l) {
        const short* qkv_l = wqkvT + (size_t)l * 196608;
        const short* wo_l = woT + (size_t)l * 65536;
        const short* w1_l = w1T + (size_t)l * 262144;
        const short* w2_l = w2T + (size_t)l * 262144;
        int last = (l == NLAYERS - 1);

        gemm_qkv<<<dim3(6, M2 / 128), 256, 0, stream>>>(xb, qkv_l, bq + l * 256, bk + l * 256,
                                                        bv + l * 256, C0, C1, C2);
        transpose_v<<<dim3(20, BATCH * NH), 256, 0, stream>>>(C2, C4);
        attn_fused<<<dim3(2, BATCH * NH), 256, 0, stream>>>(C0, C1, C4, C3);
        pad_attn<<<BATCH, 256, 0, stream>>>(C0, C1, C2, C3);
        // h1 = LN1(x + ctx@Wo + bo) for ALL rows (incl. pad): reads C3 + xb, writes C0.
        gemm_wo_ln<<<M2 / 64, 256, 0, stream>>>(C3, wo_l, bo + l * 256, xb,
                                                ln1g + l * 256, ln1b + l * 256, C0);
        // x = LN2(h1 + ffn(h1)) for ALL rows: reads C0, writes xb (last: fout + padrowF).
        ff_fused<<<M2 / 64, 256, 0, stream>>>(C0, w1_l, b1 + l * 1024, w2_l, b2 + l * 256,
                                              ln2g + l * 256, ln2b + l * 256, xb,
                                              last ? (float*)d_out : nullptr,
                                              last ? padrowF : nullptr);
        if (last)
            pad_bcast<<<dim3(96, BATCH), 256, 0, stream>>>(padrowF, (float*)d_out);
    }
}